// Round 1
// baseline (3469.102 us; speedup 1.0000x reference)
//
#include <hip/hip_runtime.h>
#include <stdint.h>

typedef unsigned long long u64;

// ---------------------------------------------------------------------------
// Pack input x [256,3,32,32] f32 -> A0 [256][32][32][1] u64 (bits 0..2 = sign>0)
// ---------------------------------------------------------------------------
__global__ void pack_input_kernel(const float* __restrict__ x, u64* __restrict__ a0)
{
    int idx = blockIdx.x * blockDim.x + threadIdx.x; // b*1024 + pix
    if (idx >= 256 * 1024) return;
    int b = idx >> 10, pix = idx & 1023;
    const float* xp = x + (size_t)b * 3 * 1024 + pix;
    u64 wd = 0;
    if (xp[0]    > 0.f) wd |= 1ull;
    if (xp[1024] > 0.f) wd |= 2ull;
    if (xp[2048] > 0.f) wd |= 4ull;
    a0[idx] = wd;
}

// ---------------------------------------------------------------------------
// Pack conv weights [O][C][3][3] f32 -> [G][9][KW][64] u64
//   bit c2 of word (g,t,wi,sl): channel c = wi*64+c2, oc = g*64+sl
// ---------------------------------------------------------------------------
__global__ void pack_weights_kernel(const float* __restrict__ w, u64* __restrict__ wp,
                                    int O, int C, int KW)
{
    int idx = blockIdx.x * blockDim.x + threadIdx.x;
    int total = O * 9 * KW;
    if (idx >= total) return;
    int wi = idx % KW;
    int t  = (idx / KW) % 9;
    int o  = idx / (KW * 9);
    int g = o >> 6, sl = o & 63;
    const float* ws = w + (size_t)o * C * 9 + t;
    u64 word = 0;
    int cbase = wi * 64;
    int cend = C - cbase; if (cend > 64) cend = 64;
    for (int c2 = 0; c2 < cend; ++c2) {
        if (ws[(size_t)(cbase + c2) * 9] > 0.f) word |= (1ull << c2);
    }
    wp[((((size_t)g * 9 + t) * KW + wi) << 6) + sl] = word;
}

// ---------------------------------------------------------------------------
// Pack fc weights [10][15568] f32 -> [10][16 pix][16 words] u64 matching the
// activation layout [B][pix][word]: flatten index j = c*16 + p  (CHW order)
// ---------------------------------------------------------------------------
__global__ void pack_fc_kernel(const float* __restrict__ fcw, u64* __restrict__ wfc)
{
    int idx = blockIdx.x * blockDim.x + threadIdx.x; // k*256 + p*16 + w
    if (idx >= 10 * 256) return;
    int w = idx & 15;
    int p = (idx >> 4) & 15;
    int k = idx >> 8;
    u64 word = 0;
    for (int c2 = 0; c2 < 64; ++c2) {
        int c = w * 64 + c2;
        if (c < 973) {
            if (fcw[(size_t)k * 15568 + c * 16 + p] > 0.f) word |= (1ull << c2);
        }
    }
    wfc[idx] = word;
}

// ---------------------------------------------------------------------------
// Binary conv 3x3 pad 1 (+ optional 2x2 maxpool) + BN-sign, fully bit-packed.
// Block = 64 threads = 1 wave = one 8x8 conv-pixel tile of image b, one group
// of 64 output channels (g = blockIdx.y). Lane = conv pixel. 8 oc register-
// blocked in the inner loop; weights are wave-uniform -> scalar loads.
//   act: [B][H][W][KW] u64,  wp: [G][9][KW][64],  bnp: [4][Cout] f32
//   out: [B][OH][OW][OCW] u64  (OH=H/2 if POOL else H)
// ---------------------------------------------------------------------------
template <int KW, int KWP, bool POOL>
__global__ __launch_bounds__(64)
void bconv_kernel(const u64* __restrict__ act, const u64* __restrict__ wp,
                  const float* __restrict__ bnp, u64* __restrict__ out,
                  int H, int W, int Cin, int Cout, int OCW, int tX)
{
    __shared__ u64 sa[100 * KWP];
    int lane = threadIdx.x;
    int tiles = tX * tX;
    int b  = blockIdx.x / tiles;
    int t0 = blockIdx.x % tiles;
    int ti = t0 / tX, tj = t0 - ti * tX;
    int i0 = ti * 8, j0 = tj * 8;
    int g = blockIdx.y;

    // stage halo'd tile: rows i0-1..i0+8, cols j0-1..j0+8
    int nw = 100 * KW;
    for (int q = lane; q < nw; q += 64) {
        int cell = q / KW, w = q - cell * KW;
        int r = cell / 10, c = cell - r * 10;
        int gi = i0 - 1 + r, gj = j0 - 1 + c;
        u64 v = 0;
        if ((unsigned)gi < (unsigned)H && (unsigned)gj < (unsigned)W)
            v = act[(((size_t)b * H + gi) * W + gj) * KW + w];
        sa[cell * KWP + w] = v;
    }
    __syncthreads();

    int i = lane >> 3, j = lane & 7;
    int gi = i0 + i, gj = j0 + j;

    u64 packed = 0;
    for (int sub = 0; sub < 8; ++sub) {
        int ocb = (g << 6) + (sub << 3);
        if (ocb >= Cout) break;
        int acc[8];
#pragma unroll
        for (int k = 0; k < 8; ++k) acc[k] = 0;

        for (int t = 0; t < 9; ++t) {
            int ky = t / 3, kx = t - ky * 3;
            int rr = gi + ky - 1, cc = gj + kx - 1;
            int vm = ((unsigned)rr < (unsigned)H) && ((unsigned)cc < (unsigned)W);
            const u64* sp = &sa[((i + ky) * 10 + (j + kx)) * KWP];
            const u64* wq = wp + ((((size_t)g * 9 + t) * KW) << 6) + (sub << 3);
            int pop[8];
#pragma unroll
            for (int k = 0; k < 8; ++k) pop[k] = 0;
#pragma unroll 4
            for (int w = 0; w < KW; ++w) {
                u64 a = sp[w];
#pragma unroll
                for (int k = 0; k < 8; ++k)
                    pop[k] += __popcll(a ^ wq[(w << 6) + k]);
            }
#pragma unroll
            for (int k = 0; k < 8; ++k)
                acc[k] += vm * (Cin - 2 * pop[k]);
        }
#pragma unroll
        for (int k = 0; k < 8; ++k) {
            int oc = ocb + k;
            float ga = bnp[oc];
            float be = bnp[Cout + oc];
            float mm = bnp[2 * Cout + oc];
            float vv = bnp[3 * Cout + oc];
            // bn value of the integer conv output; sign decision is exact since
            // beta=0, gamma=1 -> reduces to (y > m); kept general anyway.
            float bnv = ((float)acc[k] - mm) * (ga * rsqrtf(vv + 1e-5f)) + be;
            if (oc < Cout && bnv > 0.f) packed |= (1ull << (sub * 8 + k));
        }
    }

    if (POOL) {
        // pool-before-bn, scale>0 => pooled sign bit = OR over 2x2 window
        packed |= __shfl_xor(packed, 1);
        packed |= __shfl_xor(packed, 8);
        if ((lane & 9) == 0) {
            int OH = H >> 1, OW = W >> 1;
            int oi = gi >> 1, oj = gj >> 1;
            out[(((size_t)b * OH + oi) * OW + oj) * OCW + g] = packed;
        }
    } else {
        out[(((size_t)b * H + gi) * W + gj) * OCW + g] = packed;
    }
}

// ---------------------------------------------------------------------------
// FC: out[b][k] = 15568 - 2*popcount(a6[b] ^ wfc[k]) + fcb[k]
// ---------------------------------------------------------------------------
__global__ void fc_kernel(const u64* __restrict__ a6, const u64* __restrict__ wfc,
                          const float* __restrict__ fcb, float* __restrict__ out)
{
    int idx = blockIdx.x * blockDim.x + threadIdx.x;
    if (idx >= 2560) return;
    int k = idx % 10, b = idx / 10;
    const u64* ap = a6 + (size_t)b * 256;
    const u64* wq = wfc + (size_t)k * 256;
    int pop = 0;
#pragma unroll 8
    for (int q = 0; q < 256; ++q) pop += __popcll(ap[q] ^ wq[q]);
    out[idx] = (float)(15568 - 2 * pop) + fcb[k];
}

// ---------------------------------------------------------------------------
// launch
// ---------------------------------------------------------------------------
extern "C" void kernel_launch(void* const* d_in, const int* in_sizes, int n_in,
                              void* d_out, int out_size, void* d_ws, size_t ws_size,
                              hipStream_t stream)
{
    // setup_inputs dict order: x, w0,p0, w1,p1, w2,p2, w3,p3, w4,p4, w5,p5, fcw, fcb
    const float* x   = (const float*)d_in[0];
    const float* w0  = (const float*)d_in[1];
    const float* p0  = (const float*)d_in[2];
    const float* w1  = (const float*)d_in[3];
    const float* p1  = (const float*)d_in[4];
    const float* w2  = (const float*)d_in[5];
    const float* p2  = (const float*)d_in[6];
    const float* w3  = (const float*)d_in[7];
    const float* p3  = (const float*)d_in[8];
    const float* w4  = (const float*)d_in[9];
    const float* p4  = (const float*)d_in[10];
    const float* w5  = (const float*)d_in[11];
    const float* p5  = (const float*)d_in[12];
    const float* fcw = (const float*)d_in[13];
    const float* fcb = (const float*)d_in[14];
    float* out = (float*)d_out;

    u64* ws = (u64*)d_ws;
    u64* A0 = ws;              // [256][32][32][1]   = 262144
    u64* A1 = A0 + 262144;     // [256][32][32][6]   = 1572864
    u64* A2 = A1 + 1572864;    // [256][16][16][6]   = 393216
    u64* A3 = A2 + 393216;     // [256][16][16][11]  = 720896
    u64* A4 = A3 + 720896;     // [256][8][8][11]    = 180224
    u64* A5 = A4 + 180224;     // [256][8][8][20]    = 327680
    u64* A6 = A5 + 327680;     // [256][4][4][16]    = 65536
    u64* W0p = A6 + 65536;     // 384*9*1   = 3456
    u64* W1p = W0p + 3456;     // 384*9*6   = 20736
    u64* W2p = W1p + 20736;    // 704*9*6   = 38016
    u64* W3p = W2p + 38016;    // 704*9*11  = 69696
    u64* W4p = W3p + 69696;    // 1280*9*11 = 126720
    u64* W5p = W4p + 126720;   // 1024*9*20 = 184320
    u64* WFp = W5p + 184320;   // 10*256    = 2560

    pack_input_kernel<<<1024, 256, 0, stream>>>(x, A0);
    pack_weights_kernel<<<(344 * 9 * 1 + 255) / 256, 256, 0, stream>>>(w0, W0p, 344, 3, 1);
    pack_weights_kernel<<<(352 * 9 * 6 + 255) / 256, 256, 0, stream>>>(w1, W1p, 352, 344, 6);
    pack_weights_kernel<<<(686 * 9 * 6 + 255) / 256, 256, 0, stream>>>(w2, W2p, 686, 352, 6);
    pack_weights_kernel<<<(679 * 9 * 11 + 255) / 256, 256, 0, stream>>>(w3, W3p, 679, 686, 11);
    pack_weights_kernel<<<(1246 * 9 * 11 + 255) / 256, 256, 0, stream>>>(w4, W4p, 1246, 679, 11);
    pack_weights_kernel<<<(973 * 9 * 20 + 255) / 256, 256, 0, stream>>>(w5, W5p, 973, 1246, 20);
    pack_fc_kernel<<<10, 256, 0, stream>>>(fcw, WFp);

    dim3 blk(64);
    // L0: conv(sign(x), sign(w0)) 32x32, Cin=3(KW=1) -> Cout=344 (OCW=6)
    bconv_kernel<1, 1, false><<<dim3(256 * 16, 6), blk, 0, stream>>>(A0, W0p, p0, A1, 32, 32, 3, 344, 6, 4);
    // L1: 32x32 conv + pool -> 16x16, Cin=344(KW=6) -> Cout=352 (OCW=6)
    bconv_kernel<6, 7, true><<<dim3(256 * 16, 6), blk, 0, stream>>>(A1, W1p, p1, A2, 32, 32, 344, 352, 6, 4);
    // L2: 16x16, Cin=352(KW=6) -> Cout=686 (OCW=11)
    bconv_kernel<6, 7, false><<<dim3(256 * 4, 11), blk, 0, stream>>>(A2, W2p, p2, A3, 16, 16, 352, 686, 11, 2);
    // L3: 16x16 conv + pool -> 8x8, Cin=686(KW=11) -> Cout=679 (OCW=11)
    bconv_kernel<11, 11, true><<<dim3(256 * 4, 11), blk, 0, stream>>>(A3, W3p, p3, A4, 16, 16, 686, 679, 11, 2);
    // L4: 8x8, Cin=679(KW=11) -> Cout=1246 (OCW=20)
    bconv_kernel<11, 11, false><<<dim3(256 * 1, 20), blk, 0, stream>>>(A4, W4p, p4, A5, 8, 8, 679, 1246, 20, 1);
    // L5: 8x8 conv + pool -> 4x4, Cin=1246(KW=20,KWP=21) -> Cout=973 (OCW=16)
    bconv_kernel<20, 21, true><<<dim3(256 * 1, 16), blk, 0, stream>>>(A5, W5p, p5, A6, 8, 8, 1246, 973, 16, 1);
    // FC: [256,10]
    fc_kernel<<<10, 256, 0, stream>>>(A6, WFp, fcb, out);
}

// Round 2
// 3226.828 us; speedup vs baseline: 1.0751x; 1.0751x over previous
//
#include <hip/hip_runtime.h>
#include <stdint.h>

typedef unsigned long long u64;

// ---------------------------------------------------------------------------
// Pack input x [256,3,32,32] f32 -> A0 [256][32][32][1] u64 (bits 0..2 = sign>0)
// ---------------------------------------------------------------------------
__global__ void pack_input_kernel(const float* __restrict__ x, u64* __restrict__ a0)
{
    int idx = blockIdx.x * blockDim.x + threadIdx.x; // b*1024 + pix
    if (idx >= 256 * 1024) return;
    int b = idx >> 10, pix = idx & 1023;
    const float* xp = x + (size_t)b * 3 * 1024 + pix;
    u64 wd = 0;
    if (xp[0]    > 0.f) wd |= 1ull;
    if (xp[1024] > 0.f) wd |= 2ull;
    if (xp[2048] > 0.f) wd |= 4ull;
    a0[idx] = wd;
}

// ---------------------------------------------------------------------------
// Pack conv weights [O][C][3][3] f32 -> [G][9][KW][64] u64
//   bit c2 of word (g,t,wi,sl): channel c = wi*64+c2, oc = g*64+sl
// ---------------------------------------------------------------------------
__global__ void pack_weights_kernel(const float* __restrict__ w, u64* __restrict__ wp,
                                    int O, int C, int KW)
{
    int idx = blockIdx.x * blockDim.x + threadIdx.x;
    int total = O * 9 * KW;
    if (idx >= total) return;
    int wi = idx % KW;
    int t  = (idx / KW) % 9;
    int o  = idx / (KW * 9);
    int g = o >> 6, sl = o & 63;
    const float* ws = w + (size_t)o * C * 9 + t;
    u64 word = 0;
    int cbase = wi * 64;
    int cend = C - cbase; if (cend > 64) cend = 64;
    for (int c2 = 0; c2 < cend; ++c2) {
        if (ws[(size_t)(cbase + c2) * 9] > 0.f) word |= (1ull << c2);
    }
    wp[((((size_t)g * 9 + t) * KW + wi) << 6) + sl] = word;
}

// ---------------------------------------------------------------------------
// BN -> (scale, offset): bn(y) = y*sa + sb ; sa = g*rsqrt(v+eps), sb = b - m*sa
// ---------------------------------------------------------------------------
__global__ void pack_bn_kernel(const float* __restrict__ p, float* __restrict__ sa,
                               float* __restrict__ sb, int C)
{
    int i = blockIdx.x * blockDim.x + threadIdx.x;
    if (i >= C) return;
    float g = p[i], b = p[C + i], m = p[2 * C + i], v = p[3 * C + i];
    float s = g * rsqrtf(v + 1e-5f);
    sa[i] = s;
    sb[i] = fmaf(-m, s, b);
}

// ---------------------------------------------------------------------------
// Pack fc weights [10][15568] f32 -> [10][16 pix][16 words] u64 matching the
// activation layout [B][pix][word]: flatten index j = c*16 + p  (CHW order)
// ---------------------------------------------------------------------------
__global__ void pack_fc_kernel(const float* __restrict__ fcw, u64* __restrict__ wfc)
{
    int idx = blockIdx.x * blockDim.x + threadIdx.x; // k*256 + p*16 + w
    if (idx >= 10 * 256) return;
    int w = idx & 15;
    int p = (idx >> 4) & 15;
    int k = idx >> 8;
    u64 word = 0;
    for (int c2 = 0; c2 < 64; ++c2) {
        int c = w * 64 + c2;
        if (c < 973) {
            if (fcw[(size_t)k * 15568 + c * 16 + p] > 0.f) word |= (1ull << c2);
        }
    }
    wfc[idx] = word;
}

// ---------------------------------------------------------------------------
// Binary conv 3x3 pad 1 (+ optional 2x2 maxpool) + BN-sign, bit-packed.
// Block = 64 threads = 1 wave = one 8x8 conv-pixel tile x one 64-oc group.
// Inner loop: 16-oc register blocking, pure xor + accumulating bcnt
// (4 VALU per 64-channel word-pair). Validity mask applied per-tap as
// and+add; y = Cin*Nvalid - 2*popsum.
//   act: [B][H][W][KW] u64,  wp: [G][9][KW][64],  out: [B][OH][OW][OCW] u64
// ---------------------------------------------------------------------------
template <int KW, int KWP, bool POOL>
__global__ __launch_bounds__(64)
void bconv_kernel(const u64* __restrict__ act, const u64* __restrict__ wp,
                  const float* __restrict__ sA, const float* __restrict__ sB,
                  u64* __restrict__ out,
                  int H, int W, int Cin, int Cout, int OCW, int tX)
{
    __shared__ u64 sa[100 * KWP];
    const int lane = threadIdx.x;
    const int tiles = tX * tX;
    const int b  = blockIdx.x / tiles;
    const int t0 = blockIdx.x % tiles;
    const int ti = t0 / tX, tj = t0 - ti * tX;
    const int i0 = ti * 8, j0 = tj * 8;
    const int g = blockIdx.y;

    // stage halo'd tile: rows i0-1..i0+8, cols j0-1..j0+8 (zeros outside image)
    const int nw = 100 * KW;
    for (int q = lane; q < nw; q += 64) {
        int cell = q / KW, w = q - cell * KW;
        int r = cell / 10, c = cell - r * 10;
        int gi_ = i0 - 1 + r, gj_ = j0 - 1 + c;
        u64 v = 0;
        if ((unsigned)gi_ < (unsigned)H && (unsigned)gj_ < (unsigned)W)
            v = act[(((size_t)b * H + gi_) * W + gj_) * KW + w];
        sa[cell * KWP + w] = v;
    }
    __syncthreads();

    const int i = lane >> 3, j = lane & 7;
    const int gi = i0 + i, gj = j0 + j;

    // per-lane tap validity mask + count (computed once)
    unsigned vmask = 0;
    int Nv = 0;
#pragma unroll
    for (int t = 0; t < 9; ++t) {
        int ky = t / 3, kx = t - (t / 3) * 3;
        int ok = (((unsigned)(gi + ky - 1) < (unsigned)H) &
                  ((unsigned)(gj + kx - 1) < (unsigned)W)) ? 1 : 0;
        vmask |= (unsigned)ok << t;
        Nv += ok;
    }
    const int yb = Cin * Nv;  // hoisted: the only integer multiply

    u64 packed = 0;
    for (int sub = 0; sub < 4; ++sub) {
        const int ocb = (g << 6) + (sub << 4);
        if (ocb >= Cout) break;

        int popsum[16];
#pragma unroll
        for (int k = 0; k < 16; ++k) popsum[k] = 0;

#pragma unroll 1
        for (int t = 0; t < 9; ++t) {
            const int ky = t / 3, kx = t - ky * 3;
            const u64* sp = &sa[((i + ky) * 10 + (j + kx)) * KWP];
            const u64* wq = wp + ((((size_t)g * 9 + t) * KW) << 6) + (sub << 4);
            const int msk = -(int)((vmask >> t) & 1u);

            int pt[16];
#pragma unroll
            for (int k = 0; k < 16; ++k) pt[k] = 0;

#pragma unroll 2
            for (int w = 0; w < KW; ++w) {
                u64 a = sp[w];
                unsigned alo = (unsigned)a, ahi = (unsigned)(a >> 32);
#pragma unroll
                for (int k = 0; k < 16; ++k) {
                    u64 wv = wq[(w << 6) + k];        // wave-uniform -> s_load
                    pt[k] += __popc(alo ^ (unsigned)wv);
                    pt[k] += __popc(ahi ^ (unsigned)(wv >> 32));
                }
            }
#pragma unroll
            for (int k = 0; k < 16; ++k) popsum[k] += pt[k] & msk;
        }

#pragma unroll
        for (int k = 0; k < 16; ++k) {
            int oc = ocb + k;
            int occ = oc < Cout ? oc : 0;             // clamp: no OOB loads
            int y = yb - 2 * popsum[k];
            float bnv = fmaf((float)y, sA[occ], sB[occ]);
            if (oc < Cout && bnv > 0.f) packed |= (1ull << (sub * 16 + k));
        }
    }

    if (POOL) {
        // pool-before-bn with scale>0 => pooled sign bit = OR over 2x2 window
        packed |= __shfl_xor(packed, 1);
        packed |= __shfl_xor(packed, 8);
        if ((lane & 9) == 0) {
            int OH = H >> 1, OW = W >> 1;
            int oi = gi >> 1, oj = gj >> 1;
            out[(((size_t)b * OH + oi) * OW + oj) * OCW + g] = packed;
        }
    } else {
        out[(((size_t)b * H + gi) * W + gj) * OCW + g] = packed;
    }
}

// ---------------------------------------------------------------------------
// FC: out[b][k] = 15568 - 2*popcount(a6[b] ^ wfc[k]) + fcb[k]
// ---------------------------------------------------------------------------
__global__ void fc_kernel(const u64* __restrict__ a6, const u64* __restrict__ wfc,
                          const float* __restrict__ fcb, float* __restrict__ out)
{
    int idx = blockIdx.x * blockDim.x + threadIdx.x;
    if (idx >= 2560) return;
    int k = idx % 10, b = idx / 10;
    const u64* ap = a6 + (size_t)b * 256;
    const u64* wq = wfc + (size_t)k * 256;
    int pop = 0;
#pragma unroll 8
    for (int q = 0; q < 256; ++q) pop += __popcll(ap[q] ^ wq[q]);
    out[idx] = (float)(15568 - 2 * pop) + fcb[k];
}

// ---------------------------------------------------------------------------
// launch
// ---------------------------------------------------------------------------
extern "C" void kernel_launch(void* const* d_in, const int* in_sizes, int n_in,
                              void* d_out, int out_size, void* d_ws, size_t ws_size,
                              hipStream_t stream)
{
    const float* x   = (const float*)d_in[0];
    const float* w0  = (const float*)d_in[1];
    const float* p0  = (const float*)d_in[2];
    const float* w1  = (const float*)d_in[3];
    const float* p1  = (const float*)d_in[4];
    const float* w2  = (const float*)d_in[5];
    const float* p2  = (const float*)d_in[6];
    const float* w3  = (const float*)d_in[7];
    const float* p3  = (const float*)d_in[8];
    const float* w4  = (const float*)d_in[9];
    const float* p4  = (const float*)d_in[10];
    const float* w5  = (const float*)d_in[11];
    const float* p5  = (const float*)d_in[12];
    const float* fcw = (const float*)d_in[13];
    const float* fcb = (const float*)d_in[14];
    float* out = (float*)d_out;

    u64* ws = (u64*)d_ws;
    u64* A0 = ws;              // [256][32][32][1]   = 262144
    u64* A1 = A0 + 262144;     // [256][32][32][6]   = 1572864
    u64* A2 = A1 + 1572864;    // [256][16][16][6]   = 393216
    u64* A3 = A2 + 393216;     // [256][16][16][11]  = 720896
    u64* A4 = A3 + 720896;     // [256][8][8][11]    = 180224
    u64* A5 = A4 + 180224;     // [256][8][8][20]    = 327680
    u64* A6 = A5 + 327680;     // [256][4][4][16]    = 65536
    u64* W0p = A6 + 65536;     // 384*9*1   = 3456
    u64* W1p = W0p + 3456;     // 384*9*6   = 20736
    u64* W2p = W1p + 20736;    // 704*9*6   = 38016
    u64* W3p = W2p + 38016;    // 704*9*11  = 69696
    u64* W4p = W3p + 69696;    // 1280*9*11 = 126720
    u64* W5p = W4p + 126720;   // 1024*9*20 = 184320
    u64* WFp = W5p + 184320;   // 10*256    = 2560
    // BN scale/offset arrays (each padded to 1280 floats = 160 u64)
    float* SA0 = (float*)(WFp + 2560);
    float* SB0 = SA0 + 1280;
    float* SA1 = SB0 + 1280;
    float* SB1 = SA1 + 1280;
    float* SA2 = SB1 + 1280;
    float* SB2 = SA2 + 1280;
    float* SA3 = SB2 + 1280;
    float* SB3 = SA3 + 1280;
    float* SA4 = SB3 + 1280;
    float* SB4 = SA4 + 1280;
    float* SA5 = SB4 + 1280;
    float* SB5 = SA5 + 1280;

    pack_input_kernel<<<1024, 256, 0, stream>>>(x, A0);
    pack_weights_kernel<<<(344 * 9 * 1 + 255) / 256, 256, 0, stream>>>(w0, W0p, 344, 3, 1);
    pack_weights_kernel<<<(352 * 9 * 6 + 255) / 256, 256, 0, stream>>>(w1, W1p, 352, 344, 6);
    pack_weights_kernel<<<(686 * 9 * 6 + 255) / 256, 256, 0, stream>>>(w2, W2p, 686, 352, 6);
    pack_weights_kernel<<<(679 * 9 * 11 + 255) / 256, 256, 0, stream>>>(w3, W3p, 679, 686, 11);
    pack_weights_kernel<<<(1246 * 9 * 11 + 255) / 256, 256, 0, stream>>>(w4, W4p, 1246, 679, 11);
    pack_weights_kernel<<<(973 * 9 * 20 + 255) / 256, 256, 0, stream>>>(w5, W5p, 973, 1246, 20);
    pack_bn_kernel<<<(344 + 255) / 256, 256, 0, stream>>>(p0, SA0, SB0, 344);
    pack_bn_kernel<<<(352 + 255) / 256, 256, 0, stream>>>(p1, SA1, SB1, 352);
    pack_bn_kernel<<<(686 + 255) / 256, 256, 0, stream>>>(p2, SA2, SB2, 686);
    pack_bn_kernel<<<(679 + 255) / 256, 256, 0, stream>>>(p3, SA3, SB3, 679);
    pack_bn_kernel<<<(1246 + 255) / 256, 256, 0, stream>>>(p4, SA4, SB4, 1246);
    pack_bn_kernel<<<(973 + 255) / 256, 256, 0, stream>>>(p5, SA5, SB5, 973);
    pack_fc_kernel<<<10, 256, 0, stream>>>(fcw, WFp);

    dim3 blk(64);
    bconv_kernel<1, 1, false><<<dim3(256 * 16, 6), blk, 0, stream>>>(A0, W0p, SA0, SB0, A1, 32, 32, 3, 344, 6, 4);
    bconv_kernel<6, 7, true><<<dim3(256 * 16, 6), blk, 0, stream>>>(A1, W1p, SA1, SB1, A2, 32, 32, 344, 352, 6, 4);
    bconv_kernel<6, 7, false><<<dim3(256 * 4, 11), blk, 0, stream>>>(A2, W2p, SA2, SB2, A3, 16, 16, 352, 686, 11, 2);
    bconv_kernel<11, 11, true><<<dim3(256 * 4, 11), blk, 0, stream>>>(A3, W3p, SA3, SB3, A4, 16, 16, 686, 679, 11, 2);
    bconv_kernel<11, 11, false><<<dim3(256 * 1, 20), blk, 0, stream>>>(A4, W4p, SA4, SB4, A5, 8, 8, 679, 1246, 20, 1);
    bconv_kernel<20, 21, true><<<dim3(256 * 1, 16), blk, 0, stream>>>(A5, W5p, SA5, SB5, A6, 8, 8, 1246, 973, 16, 1);
    fc_kernel<<<10, 256, 0, stream>>>(A6, WFp, fcb, out);
}

// Round 4
// 1527.397 us; speedup vs baseline: 2.2713x; 2.1126x over previous
//
#include <hip/hip_runtime.h>
#include <stdint.h>

typedef unsigned long long u64;
typedef int v4i  __attribute__((ext_vector_type(4)));
typedef int v16i __attribute__((ext_vector_type(16)));

static __device__ __forceinline__ v16i mfma_i8(v4i a, v4i b, v16i c) {
    return __builtin_amdgcn_mfma_i32_32x32x32_i8(a, b, c, 0, 0, 0);
}
static __device__ __forceinline__ int imax2(int a, int b) { return a > b ? a : b; }

// ---------------------------------------------------------------------------
// Pack input x [256,3,32,32] f32 -> A0 [256][32][32][1] u64 (bits 0..2 = sign>0)
// ---------------------------------------------------------------------------
__global__ void pack_input_kernel(const float* __restrict__ x, u64* __restrict__ a0)
{
    int idx = blockIdx.x * blockDim.x + threadIdx.x;
    if (idx >= 256 * 1024) return;
    int b = idx >> 10, pix = idx & 1023;
    const float* xp = x + (size_t)b * 3072 + pix;
    u64 wd = 0;
    if (xp[0]    > 0.f) wd |= 1ull;
    if (xp[1024] > 0.f) wd |= 2ull;
    if (xp[2048] > 0.f) wd |= 4ull;
    a0[idx] = wd;
}

// ---------------------------------------------------------------------------
// w [O][C][3][3] f32 -> B-fragment i8 slab:
//   v4i index = ((t*KC + kc)*OCG + og)*64 + lane ; byte j of that v4i:
//   oc = og*32 + (lane&31), c = kc*32 + (lane>>5)*16 + j ; 0 if oc>=O or c>=C
// ---------------------------------------------------------------------------
__global__ void pack_w_i8(const float* __restrict__ w, char* __restrict__ wb,
                          int O, int C, int KC, int OCG)
{
    int idx = blockIdx.x * blockDim.x + threadIdx.x;
    int total = 9 * KC * OCG * 64;
    if (idx >= total) return;
    int lane = idx & 63;
    int rest = idx >> 6;
    int og = rest % OCG; rest /= OCG;
    int kc = rest % KC;  int t = rest / KC;
    int oc = og * 32 + (lane & 31);
    int cb = kc * 32 + (lane >> 5) * 16;
    char vals[16];
#pragma unroll
    for (int j = 0; j < 16; ++j) {
        int c = cb + j;
        char v = 0;
        if (oc < O && c < C)
            v = (w[(size_t)(oc * C + c) * 9 + t] > 0.f) ? (char)1 : (char)-1;
        vals[j] = v;
    }
    *(v4i*)(wb + (size_t)idx * 16) = *(v4i*)vals;
}

// ---------------------------------------------------------------------------
// BN -> (scale, offset): bn(y) = y*sa + sb
// ---------------------------------------------------------------------------
__global__ void pack_bn_kernel(const float* __restrict__ p, float* __restrict__ sa,
                               float* __restrict__ sb, int C)
{
    int i = blockIdx.x * blockDim.x + threadIdx.x;
    if (i >= C) return;
    float g = p[i], b = p[C + i], m = p[2 * C + i], v = p[3 * C + i];
    float s = g * rsqrtf(v + 1e-5f);
    sa[i] = s;
    sb[i] = fmaf(-m, s, b);
}

// ---------------------------------------------------------------------------
// Pack fc weights [10][15568] f32 -> [10][16 pix][16 words] u64 matching the
// activation layout [B][pix][word]: flatten index j = c*16 + p  (CHW order)
// ---------------------------------------------------------------------------
__global__ void pack_fc_kernel(const float* __restrict__ fcw, u64* __restrict__ wfc)
{
    int idx = blockIdx.x * blockDim.x + threadIdx.x; // k*256 + p*16 + w
    if (idx >= 10 * 256) return;
    int w = idx & 15;
    int p = (idx >> 4) & 15;
    int k = idx >> 8;
    u64 word = 0;
    for (int c2 = 0; c2 < 64; ++c2) {
        int c = w * 64 + c2;
        if (c < 973) {
            if (fcw[(size_t)k * 15568 + c * 16 + p] > 0.f) word |= (1ull << c2);
        }
    }
    wfc[idx] = word;
}

// ---------------------------------------------------------------------------
// Implicit-GEMM binary conv via i8 MFMA, bit-packed global activations.
// Block = 256 thr = 4 waves. Wave = 64 px (2 A-halves) x 64 oc (2 B-groups)
// -> acc[2][2] v16i. Per 64-ch chunk: stage halo'd tile into LDS, unpacking
// u64 sign-bits -> +-1 i8 (halo cells = 0 bytes => exact zero-pad); then
// 9 taps x 2 k-subchunks x 4 MFMA. Output bit-packed via ballot.
//   act: [B][H][W][KWIN] u64, wb: B-frag slab, out: [B][OH][OW][OCW] u64
// ---------------------------------------------------------------------------
template <int H, int W, int TH, int TW, int KWIN, int OCG, int OCW, int COUT,
          bool POOL, int WM, int WN>
__global__ __launch_bounds__(256)
void conv_mfma(const u64* __restrict__ act, const v4i* __restrict__ wb,
               const float* __restrict__ sA, const float* __restrict__ sB,
               u64* __restrict__ outp)
{
    constexpr int KC = 2 * KWIN;
    constexpr int CW = TW + 2;
    constexpr int CELLS = (TH + 2) * CW;
    __shared__ __attribute__((aligned(16))) char smem[CELLS * 80];

    const int tid = threadIdx.x;
    const int lane = tid & 63;
    const int wave = tid >> 6;
    const int wm = wave % WM;
    const int wn = wave / WM;
    const int half = lane >> 5;
    const int m = lane & 31;

    constexpr int TILESX = W / TW;
    constexpr int TILES = (H / TH) * TILESX;
    const int b = blockIdx.x / TILES;
    const int tl = blockIdx.x % TILES;
    const int y0 = (tl / TILESX) * TH;
    const int x0 = (tl % TILESX) * TW;

    const int ocg0 = blockIdx.y * (WN * 2) + wn * 2;
    const int oc0 = ocg0 * 32;
    const int gw = ocg0 >> 1;          // output u64 word index

    int abase[2];
#pragma unroll
    for (int ph = 0; ph < 2; ++ph) {
        int p = (wm * 2 + ph) * 32 + m;
        int py = p / TW, px = p % TW;
        abase[ph] = (py * CW + px) * 80 + half * 16;
    }

    v16i acc[2][2];
#pragma unroll
    for (int a = 0; a < 2; ++a)
#pragma unroll
        for (int o = 0; o < 2; ++o)
#pragma unroll
            for (int i = 0; i < 16; ++i) acc[a][o][i] = 0;

    const u64* actb = act + (size_t)b * H * W * KWIN;

    for (int c64 = 0; c64 < KWIN; ++c64) {
        // ---- stage + unpack one 64-channel chunk ----
        for (int cell = tid; cell < CELLS; cell += 256) {
            int cy = cell / CW, cx = cell % CW;
            int gy = y0 + cy - 1, gx = x0 + cx - 1;
            char* dst = smem + cell * 80;
            if ((unsigned)gy < (unsigned)H && (unsigned)gx < (unsigned)W) {
                u64 wd = actb[((size_t)gy * W + gx) * KWIN + c64];
#pragma unroll
                for (int s = 0; s < 4; ++s) {
                    v4i v;
#pragma unroll
                    for (int q = 0; q < 4; ++q) {
                        unsigned nib = (unsigned)(wd >> (s * 16 + q * 4)) & 0xfu;
                        unsigned spread = (nib * 0x00204081u) & 0x01010101u;
                        v[q] = (int)(0x01010101u + (spread ^ 0x01010101u) * 0xfeu);
                    }
                    *(v4i*)(dst + s * 16) = v;
                }
            } else {
                v4i z; z[0] = 0; z[1] = 0; z[2] = 0; z[3] = 0;
#pragma unroll
                for (int s = 0; s < 4; ++s) *(v4i*)(dst + s * 16) = z;
            }
        }
        __syncthreads();

#pragma unroll
        for (int t = 0; t < 9; ++t) {
            const int cofs = ((t / 3) * CW + (t % 3)) * 80;
#pragma unroll
            for (int ks = 0; ks < 2; ++ks) {
                v4i a0 = *(const v4i*)(smem + abase[0] + cofs + ks * 32);
                v4i a1 = *(const v4i*)(smem + abase[1] + cofs + ks * 32);
                const v4i* bp = wb + ((size_t)((t * KC + c64 * 2 + ks) * OCG + ocg0)) * 64 + lane;
                v4i b0 = bp[0];
                v4i b1 = bp[64];
                acc[0][0] = mfma_i8(a0, b0, acc[0][0]);
                acc[0][1] = mfma_i8(a0, b1, acc[0][1]);
                acc[1][0] = mfma_i8(a1, b0, acc[1][0]);
                acc[1][1] = mfma_i8(a1, b1, acc[1][1]);
            }
        }
        __syncthreads();
    }

    // ---- epilogue: (pool) + BN-sign -> ballot-packed u64 stores ----
    const int ocA = oc0 + m;
    const int ocB = oc0 + 32 + m;
    const float fa0 = sA[ocA < COUT ? ocA : 0], fb0 = sB[ocA < COUT ? ocA : 0];
    const float fa1 = sA[ocB < COUT ? ocB : 0], fb1 = sB[ocB < COUT ? ocB : 0];

#pragma unroll
    for (int ph = 0; ph < 2; ++ph) {
        if constexpr (POOL) {
#pragma unroll
            for (int gi = 0; gi < 4; ++gi) {
                constexpr int XB = (TW == 16) ? 8 : 4;
                const int g = (TW == 16) ? (gi * 2) : ((gi & 1) * 2 + (gi >> 1) * 8);
                int v0 = imax2(imax2(acc[ph][0][g], acc[ph][0][g ^ 1]),
                               imax2(acc[ph][0][g ^ XB], acc[ph][0][(g ^ XB) | 1]));
                int v1 = imax2(imax2(acc[ph][1][g], acc[ph][1][g ^ 1]),
                               imax2(acc[ph][1][g ^ XB], acc[ph][1][(g ^ XB) | 1]));
                u64 b0 = __ballot((ocA < COUT) && (fmaf((float)v0, fa0, fb0) > 0.f));
                u64 b1 = __ballot((ocB < COUT) && (fmaf((float)v1, fa1, fb1) > 0.f));
                u64 w_lo = (b0 & 0xffffffffull) | (b1 << 32);
                u64 w_hi = (b0 >> 32) | (b1 & 0xffffffff00000000ull);
                int pyo, pxo_h0, pxo_h1;
                if (TW == 16) {
                    pyo = wm * 2 + ph;
                    pxo_h0 = ((g >> 1) & 1) | (((g >> 2) & 1) << 2);
                    pxo_h1 = pxo_h0 | 2;
                } else {
                    pyo = (wm * 2 + ph) * 2 + ((g >> 3) & 1);
                    pxo_h0 = ((g >> 1) & 1);
                    pxo_h1 = pxo_h0 | 2;
                }
                if (gw < OCW) {
                    size_t rowbase = ((size_t)b * (H / 2) + (y0 / 2 + pyo)) * (W / 2);
                    if (lane == ph * 8 + gi * 2)
                        outp[(rowbase + (x0 / 2 + pxo_h0)) * OCW + gw] = w_lo;
                    else if (lane == ph * 8 + gi * 2 + 1)
                        outp[(rowbase + (x0 / 2 + pxo_h1)) * OCW + gw] = w_hi;
                }
            }
        } else {
#pragma unroll
            for (int reg = 0; reg < 16; ++reg) {
                u64 b0 = __ballot((ocA < COUT) && (fmaf((float)acc[ph][0][reg], fa0, fb0) > 0.f));
                u64 b1 = __ballot((ocB < COUT) && (fmaf((float)acc[ph][1][reg], fa1, fb1) > 0.f));
                u64 w_lo = (b0 & 0xffffffffull) | (b1 << 32);
                u64 w_hi = (b0 >> 32) | (b1 & 0xffffffff00000000ull);
                int row = (reg & 3) + 8 * (reg >> 2);
                int p_lo = (wm * 2 + ph) * 32 + row;
                int p_hi = p_lo + 4;
                if (gw < OCW) {
                    if (lane == reg * 2) {
                        int py = p_lo / TW, px = p_lo % TW;
                        outp[(((size_t)b * H + (y0 + py)) * W + (x0 + px)) * OCW + gw] = w_lo;
                    } else if (lane == reg * 2 + 1) {
                        int py = p_hi / TW, px = p_hi % TW;
                        outp[(((size_t)b * H + (y0 + py)) * W + (x0 + px)) * OCW + gw] = w_hi;
                    }
                }
            }
        }
    }
}

// ---------------------------------------------------------------------------
// FC: out[b][k] = 15568 - 2*popcount(a6[b] ^ wfc[k]) + fcb[k]   (exact)
// ---------------------------------------------------------------------------
__global__ void fc_kernel(const u64* __restrict__ a6, const u64* __restrict__ wfc,
                          const float* __restrict__ fcb, float* __restrict__ out)
{
    int idx = blockIdx.x * blockDim.x + threadIdx.x;
    if (idx >= 2560) return;
    int k = idx % 10, b = idx / 10;
    const u64* ap = a6 + (size_t)b * 256;
    const u64* wq = wfc + (size_t)k * 256;
    int pop = 0;
#pragma unroll 8
    for (int q = 0; q < 256; ++q) pop += __popcll(ap[q] ^ wq[q]);
    out[idx] = (float)(15568 - 2 * pop) + fcb[k];
}

// ---------------------------------------------------------------------------
// launch
// ---------------------------------------------------------------------------
extern "C" void kernel_launch(void* const* d_in, const int* in_sizes, int n_in,
                              void* d_out, int out_size, void* d_ws, size_t ws_size,
                              hipStream_t stream)
{
    const float* x   = (const float*)d_in[0];
    const float* w0  = (const float*)d_in[1];
    const float* p0  = (const float*)d_in[2];
    const float* w1  = (const float*)d_in[3];
    const float* p1  = (const float*)d_in[4];
    const float* w2  = (const float*)d_in[5];
    const float* p2  = (const float*)d_in[6];
    const float* w3  = (const float*)d_in[7];
    const float* p3  = (const float*)d_in[8];
    const float* w4  = (const float*)d_in[9];
    const float* p4  = (const float*)d_in[10];
    const float* w5  = (const float*)d_in[11];
    const float* p5  = (const float*)d_in[12];
    const float* fcw = (const float*)d_in[13];
    const float* fcb = (const float*)d_in[14];
    float* out = (float*)d_out;

    u64* WS = (u64*)d_ws;
    u64* A0 = WS;                  // [256][32][32][1]  = 262144
    u64* A1 = A0 + 262144;         // [256][32][32][6]  = 1572864
    u64* A2 = A1 + 1572864;        // [256][16][16][6]  = 393216
    u64* A3 = A2 + 393216;         // [256][16][16][11] = 720896
    u64* A4 = A3 + 720896;         // [256][8][8][11]   = 180224
    u64* A5 = A4 + 180224;         // [256][8][8][20]   = 327680
    u64* A6 = A5 + 327680;         // [256][4][4][16]   = 65536
    u64* WFp = A6 + 65536;         // 2560
    char* WB0 = (char*)(WFp + 2560);   //   221,184 (KC=2,  OCG=12)
    char* WB1 = WB0 + 221184;          // 1,327,104 (KC=12, OCG=12)
    char* WB2 = WB1 + 1327104;         // 2,654,208 (KC=12, OCG=24)
    char* WB3 = WB2 + 2654208;         // 4,866,048 (KC=22, OCG=24)
    char* WB4 = WB3 + 4866048;         // 8,110,080 (KC=22, OCG=40)
    char* WB5 = WB4 + 8110080;         // 11,796,480 (KC=40, OCG=32)
    float* SA0 = (float*)(WB5 + 11796480);
    float* SB0 = SA0 + 1280;
    float* SA1 = SB0 + 1280;
    float* SB1 = SA1 + 1280;
    float* SA2 = SB1 + 1280;
    float* SB2 = SA2 + 1280;
    float* SA3 = SB2 + 1280;
    float* SB3 = SA3 + 1280;
    float* SA4 = SB3 + 1280;
    float* SB4 = SA4 + 1280;
    float* SA5 = SB4 + 1280;
    float* SB5 = SA5 + 1280;
    // total ws: ~57.2 MB

    pack_input_kernel<<<1024, 256, 0, stream>>>(x, A0);
    pack_w_i8<<<(9 * 2 * 12 * 64 + 255) / 256, 256, 0, stream>>>(w0, WB0, 344, 3, 2, 12);
    pack_w_i8<<<(9 * 12 * 12 * 64 + 255) / 256, 256, 0, stream>>>(w1, WB1, 352, 344, 12, 12);
    pack_w_i8<<<(9 * 12 * 24 * 64 + 255) / 256, 256, 0, stream>>>(w2, WB2, 686, 352, 12, 24);
    pack_w_i8<<<(9 * 22 * 24 * 64 + 255) / 256, 256, 0, stream>>>(w3, WB3, 679, 686, 22, 24);
    pack_w_i8<<<(9 * 22 * 40 * 64 + 255) / 256, 256, 0, stream>>>(w4, WB4, 1246, 679, 22, 40);
    pack_w_i8<<<(9 * 40 * 32 * 64 + 255) / 256, 256, 0, stream>>>(w5, WB5, 973, 1246, 40, 32);
    pack_bn_kernel<<<2, 256, 0, stream>>>(p0, SA0, SB0, 344);
    pack_bn_kernel<<<2, 256, 0, stream>>>(p1, SA1, SB1, 352);
    pack_bn_kernel<<<3, 256, 0, stream>>>(p2, SA2, SB2, 686);
    pack_bn_kernel<<<3, 256, 0, stream>>>(p3, SA3, SB3, 679);
    pack_bn_kernel<<<5, 256, 0, stream>>>(p4, SA4, SB4, 1246);
    pack_bn_kernel<<<4, 256, 0, stream>>>(p5, SA5, SB5, 973);
    pack_fc_kernel<<<10, 256, 0, stream>>>(fcw, WFp);

    // conv layers: <H,W,TH,TW,KWIN,OCG,OCW,COUT,POOL,WM,WN>
    conv_mfma<32, 32, 8, 16,  1, 12,  6,  344, false, 2, 2>
        <<<dim3(2048, 3), 256, 0, stream>>>(A0, (const v4i*)WB0, SA0, SB0, A1);
    conv_mfma<32, 32, 8, 16,  6, 12,  6,  352, true,  2, 2>
        <<<dim3(2048, 3), 256, 0, stream>>>(A1, (const v4i*)WB1, SA1, SB1, A2);
    conv_mfma<16, 16, 8, 16,  6, 24, 11,  686, false, 2, 2>
        <<<dim3(512, 6), 256, 0, stream>>>(A2, (const v4i*)WB2, SA2, SB2, A3);
    conv_mfma<16, 16, 8, 16, 11, 24, 11,  679, true,  2, 2>
        <<<dim3(512, 6), 256, 0, stream>>>(A3, (const v4i*)WB3, SA3, SB3, A4);
    conv_mfma< 8,  8, 8,  8, 11, 40, 20, 1246, false, 1, 4>
        <<<dim3(256, 5), 256, 0, stream>>>(A4, (const v4i*)WB4, SA4, SB4, A5);
    conv_mfma< 8,  8, 8,  8, 20, 32, 16,  973, true,  1, 4>
        <<<dim3(256, 4), 256, 0, stream>>>(A5, (const v4i*)WB5, SA5, SB5, A6);

    fc_kernel<<<10, 256, 0, stream>>>(A6, WFp, fcb, out);
}

// Round 5
// 1481.522 us; speedup vs baseline: 2.3416x; 1.0310x over previous
//
#include <hip/hip_runtime.h>
#include <stdint.h>

typedef unsigned long long u64;
typedef int v4i  __attribute__((ext_vector_type(4)));
typedef int v16i __attribute__((ext_vector_type(16)));

static __device__ __forceinline__ v16i mfma_i8(v4i a, v4i b, v16i c) {
    return __builtin_amdgcn_mfma_i32_32x32x32_i8(a, b, c, 0, 0, 0);
}
static __device__ __forceinline__ int imax2(int a, int b) { return a > b ? a : b; }

// ---------------------------------------------------------------------------
// Pack input x [256,3,32,32] f32 -> A0 [256][32][32][1] u64 (bits 0..2 = sign>0)
// ---------------------------------------------------------------------------
__global__ void pack_input_kernel(const float* __restrict__ x, u64* __restrict__ a0)
{
    int idx = blockIdx.x * blockDim.x + threadIdx.x;
    if (idx >= 256 * 1024) return;
    int b = idx >> 10, pix = idx & 1023;
    const float* xp = x + (size_t)b * 3072 + pix;
    u64 wd = 0;
    if (xp[0]    > 0.f) wd |= 1ull;
    if (xp[1024] > 0.f) wd |= 2ull;
    if (xp[2048] > 0.f) wd |= 4ull;
    a0[idx] = wd;
}

// ---------------------------------------------------------------------------
// w [O][C][3][3] f32 -> B-fragment i8 slab:
//   v4i index = ((t*KC + kc)*OCG + og)*64 + lane ; byte j of that v4i:
//   oc = og*32 + (lane&31), c = kc*32 + (lane>>5)*16 + j ; 0 if oc>=O or c>=C
// ---------------------------------------------------------------------------
__global__ void pack_w_i8(const float* __restrict__ w, char* __restrict__ wb,
                          int O, int C, int KC, int OCG)
{
    int idx = blockIdx.x * blockDim.x + threadIdx.x;
    int total = 9 * KC * OCG * 64;
    if (idx >= total) return;
    int lane = idx & 63;
    int rest = idx >> 6;
    int og = rest % OCG; rest /= OCG;
    int kc = rest % KC;  int t = rest / KC;
    int oc = og * 32 + (lane & 31);
    int cb = kc * 32 + (lane >> 5) * 16;
    char vals[16];
#pragma unroll
    for (int j = 0; j < 16; ++j) {
        int c = cb + j;
        char v = 0;
        if (oc < O && c < C)
            v = (w[(size_t)(oc * C + c) * 9 + t] > 0.f) ? (char)1 : (char)-1;
        vals[j] = v;
    }
    *(v4i*)(wb + (size_t)idx * 16) = *(v4i*)vals;
}

// ---------------------------------------------------------------------------
// BN -> (scale, offset): bn(y) = y*sa + sb
// ---------------------------------------------------------------------------
__global__ void pack_bn_kernel(const float* __restrict__ p, float* __restrict__ sa,
                               float* __restrict__ sb, int C)
{
    int i = blockIdx.x * blockDim.x + threadIdx.x;
    if (i >= C) return;
    float g = p[i], b = p[C + i], m = p[2 * C + i], v = p[3 * C + i];
    float s = g * rsqrtf(v + 1e-5f);
    sa[i] = s;
    sb[i] = fmaf(-m, s, b);
}

// ---------------------------------------------------------------------------
// Pack fc weights [10][15568] f32 -> [10][16 pix][16 words] u64
// ---------------------------------------------------------------------------
__global__ void pack_fc_kernel(const float* __restrict__ fcw, u64* __restrict__ wfc)
{
    int idx = blockIdx.x * blockDim.x + threadIdx.x;
    if (idx >= 10 * 256) return;
    int w = idx & 15;
    int p = (idx >> 4) & 15;
    int k = idx >> 8;
    u64 word = 0;
    for (int c2 = 0; c2 < 64; ++c2) {
        int c = w * 64 + c2;
        if (c < 973) {
            if (fcw[(size_t)k * 15568 + c * 16 + p] > 0.f) word |= (1ull << c2);
        }
    }
    wfc[idx] = word;
}

// ---------------------------------------------------------------------------
// unpack helper: 16 sign bits -> 4 planes of 4 bytes (+1/-1), halo -> 0
// ---------------------------------------------------------------------------
static __device__ __forceinline__ int unpack4(unsigned hw, int q) {
    unsigned nib = (hw >> (4 * q)) & 0xfu;
    unsigned spread = (nib * 0x00204081u) & 0x01010101u;   // u24 mul
    return (int)(0xffffffffu ^ ((spread << 8) - (spread << 1)));
}

// ---------------------------------------------------------------------------
// Big-layer conv (16x16 tile): block = 4 waves = 256 px x 128 oc.
// Wave (wm,wn) = 128 px x 64 oc, acc[4][2] v16i. A in LDS SoA planes
// ([slab16][cell], dense 16B cells -> conflict-free b128). B from global with
// 1-step register prefetch that crosses chunk boundaries (in flight during
// staging). Output bit-packed via ballot.
// ---------------------------------------------------------------------------
template <int H, int W, int KWIN, int OCG, int OCW, int COUT, bool POOL>
__global__ __launch_bounds__(256, 2)
void conv_mfma16(const u64* __restrict__ act, const v4i* __restrict__ wb,
                 const float* __restrict__ sA, const float* __restrict__ sB,
                 u64* __restrict__ outp)
{
    constexpr int KC = 2 * KWIN;
    constexpr int CW = 18;
    constexpr int CELLS = 324;
    constexpr int PLANE = CELLS * 16;
    __shared__ __attribute__((aligned(16))) char smem[4 * PLANE];

    const int tid  = threadIdx.x;
    const int lane = tid & 63;
    const int wave = tid >> 6;
    const int wm   = wave & 1;
    const int wn   = wave >> 1;
    const int half = lane >> 5;
    const int m    = lane & 31;

    constexpr int TX = W / 16;
    constexpr int TILES = (H / 16) * TX;
    const int b  = blockIdx.x / TILES;
    const int tl = blockIdx.x % TILES;
    const int y0 = (tl / TX) * 16;
    const int x0 = (tl % TX) * 16;

    const int ocg0 = blockIdx.y * 4 + wn * 2;
    const int gw   = ocg0 >> 1;

    int aoff[4];
#pragma unroll
    for (int ag = 0; ag < 4; ++ag) {
        int p = wm * 128 + ag * 32 + m;
        aoff[ag] = ((p >> 4) * CW + (p & 15)) * 16 + half * PLANE;
    }

    v16i acc[4][2];
#pragma unroll
    for (int ag = 0; ag < 4; ++ag)
#pragma unroll
        for (int o = 0; o < 2; ++o)
#pragma unroll
            for (int i = 0; i < 16; ++i) acc[ag][o][i] = 0;

    const u64* actb = act + (size_t)b * (H * W * KWIN);

    v4i b0n, b1n;
    {
        const v4i* pn = wb + ((size_t)ocg0) * 64 + lane;
        b0n = pn[0]; b1n = pn[64];
    }

#pragma unroll 1
    for (int c64 = 0; c64 < KWIN; ++c64) {
        for (int cell = tid; cell < CELLS; cell += 256) {
            int cy = cell / CW, cx = cell % CW;
            int gy = y0 + cy - 1, gx = x0 + cx - 1;
            char* dst = smem + cell * 16;
            if ((unsigned)gy < (unsigned)H && (unsigned)gx < (unsigned)W) {
                u64 wd = actb[((size_t)gy * W + gx) * KWIN + c64];
                unsigned hv[4];
                hv[0] = (unsigned)wd & 0xffffu;
                hv[1] = ((unsigned)wd) >> 16;
                hv[2] = (unsigned)(wd >> 32) & 0xffffu;
                hv[3] = (unsigned)(wd >> 48);
#pragma unroll
                for (int s = 0; s < 4; ++s) {
                    v4i v;
#pragma unroll
                    for (int q = 0; q < 4; ++q) v[q] = unpack4(hv[s], q);
                    *(v4i*)(dst + s * PLANE) = v;
                }
            } else {
                v4i z = {0, 0, 0, 0};
#pragma unroll
                for (int s = 0; s < 4; ++s) *(v4i*)(dst + s * PLANE) = z;
            }
        }
        __syncthreads();

#pragma unroll
        for (int s = 0; s < 18; ++s) {
            v4i b0 = b0n, b1 = b1n;
            {
                const int sn = (s + 1) % 18;
                const int cn = (s == 17) ? (c64 + 1) : c64;
                const v4i* pn = wb + ((size_t)(((sn >> 1) * KC + cn * 2 + (sn & 1)) * OCG + ocg0)) * 64 + lane;
                b0n = pn[0]; b1n = pn[64];
            }
            const int t = s >> 1, ks = s & 1;
            const int toff = ((t / 3) * CW + (t % 3)) * 16 + ks * (2 * PLANE);
            v4i a0 = *(const v4i*)(smem + aoff[0] + toff);
            v4i a1 = *(const v4i*)(smem + aoff[1] + toff);
            v4i a2 = *(const v4i*)(smem + aoff[2] + toff);
            v4i a3 = *(const v4i*)(smem + aoff[3] + toff);
            acc[0][0] = mfma_i8(a0, b0, acc[0][0]);
            acc[1][0] = mfma_i8(a1, b0, acc[1][0]);
            acc[2][0] = mfma_i8(a2, b0, acc[2][0]);
            acc[3][0] = mfma_i8(a3, b0, acc[3][0]);
            acc[0][1] = mfma_i8(a0, b1, acc[0][1]);
            acc[1][1] = mfma_i8(a1, b1, acc[1][1]);
            acc[2][1] = mfma_i8(a2, b1, acc[2][1]);
            acc[3][1] = mfma_i8(a3, b1, acc[3][1]);
        }
        __syncthreads();
    }

    const int ocA = ocg0 * 32 + m;
    const int ocB = ocA + 32;
    const float fa0 = sA[ocA < COUT ? ocA : 0], fb0 = sB[ocA < COUT ? ocA : 0];
    const float fa1 = sA[ocB < COUT ? ocB : 0], fb1 = sB[ocB < COUT ? ocB : 0];

#pragma unroll
    for (int ag = 0; ag < 4; ++ag) {
        if constexpr (POOL) {
#pragma unroll
            for (int gi = 0; gi < 4; ++gi) {
                const int g = gi * 2;
                int v0 = imax2(imax2(acc[ag][0][g], acc[ag][0][g ^ 1]),
                               imax2(acc[ag][0][g ^ 8], acc[ag][0][(g ^ 8) | 1]));
                int v1 = imax2(imax2(acc[ag][1][g], acc[ag][1][g ^ 1]),
                               imax2(acc[ag][1][g ^ 8], acc[ag][1][(g ^ 8) | 1]));
                u64 bal0 = __ballot((ocA < COUT) && (fmaf((float)v0, fa0, fb0) > 0.f));
                u64 bal1 = __ballot((ocB < COUT) && (fmaf((float)v1, fa1, fb1) > 0.f));
                u64 w_lo = (bal0 & 0xffffffffull) | (bal1 << 32);
                u64 w_hi = (bal0 >> 32) | (bal1 & 0xffffffff00000000ull);
                int pyo  = wm * 4 + ag;
                int pxo0 = ((g >> 1) & 1) | (((g >> 2) & 1) << 2);
                int pxo1 = pxo0 | 2;
                if (gw < OCW) {
                    size_t rowb = ((size_t)b * (H / 2) + (y0 / 2 + pyo)) * (W / 2);
                    if (lane == (ag * 4 + gi) * 2)
                        outp[(rowb + (x0 / 2 + pxo0)) * OCW + gw] = w_lo;
                    else if (lane == (ag * 4 + gi) * 2 + 1)
                        outp[(rowb + (x0 / 2 + pxo1)) * OCW + gw] = w_hi;
                }
            }
        } else {
#pragma unroll
            for (int reg = 0; reg < 16; ++reg) {
                u64 bal0 = __ballot((ocA < COUT) && (fmaf((float)acc[ag][0][reg], fa0, fb0) > 0.f));
                u64 bal1 = __ballot((ocB < COUT) && (fmaf((float)acc[ag][1][reg], fa1, fb1) > 0.f));
                u64 w_lo = (bal0 & 0xffffffffull) | (bal1 << 32);
                u64 w_hi = (bal0 >> 32) | (bal1 & 0xffffffff00000000ull);
                int row  = (reg & 3) + 8 * (reg >> 2);
                int p_lo = wm * 128 + ag * 32 + row;
                int p_hi = p_lo + 4;
                if (gw < OCW) {
                    if (lane == reg * 2)
                        outp[(((size_t)b * H + (y0 + (p_lo >> 4))) * W + (x0 + (p_lo & 15))) * OCW + gw] = w_lo;
                    else if (lane == reg * 2 + 1)
                        outp[(((size_t)b * H + (y0 + (p_hi >> 4))) * W + (x0 + (p_hi & 15))) * OCW + gw] = w_hi;
                }
            }
        }
    }
}

// ---------------------------------------------------------------------------
// 8x8-layer conv: block = 4 waves = 4 images x 64 oc. Wave = its own image
// (64 px, acc[2][2], private LDS region), all waves share one B stream
// (L1 dedup). Same prefetch/SoA-plane scheme.
// ---------------------------------------------------------------------------
template <int KWIN, int OCG, int OCW, int COUT, bool POOL>
__global__ __launch_bounds__(256, 3)
void conv_mfma8(const u64* __restrict__ act, const v4i* __restrict__ wb,
                const float* __restrict__ sA, const float* __restrict__ sB,
                u64* __restrict__ outp)
{
    constexpr int KC = 2 * KWIN;
    constexpr int CELLS = 100;
    constexpr int PLANE = CELLS * 16;
    constexpr int IMG = 4 * PLANE;
    __shared__ __attribute__((aligned(16))) char smem[4 * IMG];

    const int tid  = threadIdx.x;
    const int lane = tid & 63;
    const int wave = tid >> 6;
    const int half = lane >> 5;
    const int m    = lane & 31;

    const int b = blockIdx.x * 4 + wave;
    const int ocg0 = blockIdx.y * 2;
    const int gw = blockIdx.y;

    int aoff[2];
#pragma unroll
    for (int ph = 0; ph < 2; ++ph) {
        int p = ph * 32 + m;
        aoff[ph] = wave * IMG + ((p >> 3) * 10 + (p & 7)) * 16 + half * PLANE;
    }

    v16i acc[2][2];
#pragma unroll
    for (int a = 0; a < 2; ++a)
#pragma unroll
        for (int o = 0; o < 2; ++o)
#pragma unroll
            for (int i = 0; i < 16; ++i) acc[a][o][i] = 0;

    const u64* actb = act + (size_t)b * (64 * KWIN);

    v4i b0n, b1n;
    {
        const v4i* pn = wb + ((size_t)ocg0) * 64 + lane;
        b0n = pn[0]; b1n = pn[64];
    }

#pragma unroll 1
    for (int c64 = 0; c64 < KWIN; ++c64) {
        for (int cell = lane; cell < CELLS; cell += 64) {
            int cy = cell / 10, cx = cell % 10;
            int gy = cy - 1, gx = cx - 1;
            char* dst = smem + wave * IMG + cell * 16;
            if ((unsigned)gy < 8u && (unsigned)gx < 8u) {
                u64 wd = actb[((size_t)gy * 8 + gx) * KWIN + c64];
                unsigned hv[4];
                hv[0] = (unsigned)wd & 0xffffu;
                hv[1] = ((unsigned)wd) >> 16;
                hv[2] = (unsigned)(wd >> 32) & 0xffffu;
                hv[3] = (unsigned)(wd >> 48);
#pragma unroll
                for (int s = 0; s < 4; ++s) {
                    v4i v;
#pragma unroll
                    for (int q = 0; q < 4; ++q) v[q] = unpack4(hv[s], q);
                    *(v4i*)(dst + s * PLANE) = v;
                }
            } else {
                v4i z = {0, 0, 0, 0};
#pragma unroll
                for (int s = 0; s < 4; ++s) *(v4i*)(dst + s * PLANE) = z;
            }
        }
        __syncthreads();

#pragma unroll
        for (int s = 0; s < 18; ++s) {
            v4i b0 = b0n, b1 = b1n;
            {
                const int sn = (s + 1) % 18;
                const int cn = (s == 17) ? (c64 + 1) : c64;
                const v4i* pn = wb + ((size_t)(((sn >> 1) * KC + cn * 2 + (sn & 1)) * OCG + ocg0)) * 64 + lane;
                b0n = pn[0]; b1n = pn[64];
            }
            const int t = s >> 1, ks = s & 1;
            const int toff = ((t / 3) * 10 + (t % 3)) * 16 + ks * (2 * PLANE);
            v4i a0 = *(const v4i*)(smem + aoff[0] + toff);
            v4i a1 = *(const v4i*)(smem + aoff[1] + toff);
            acc[0][0] = mfma_i8(a0, b0, acc[0][0]);
            acc[1][0] = mfma_i8(a1, b0, acc[1][0]);
            acc[0][1] = mfma_i8(a0, b1, acc[0][1]);
            acc[1][1] = mfma_i8(a1, b1, acc[1][1]);
        }
        __syncthreads();
    }

    const int ocA = ocg0 * 32 + m;
    const int ocB = ocA + 32;
    const float fa0 = sA[ocA < COUT ? ocA : 0], fb0 = sB[ocA < COUT ? ocA : 0];
    const float fa1 = sA[ocB < COUT ? ocB : 0], fb1 = sB[ocB < COUT ? ocB : 0];

#pragma unroll
    for (int ph = 0; ph < 2; ++ph) {
        if constexpr (POOL) {
#pragma unroll
            for (int gi = 0; gi < 4; ++gi) {
                const int g = (gi & 1) * 2 + (gi >> 1) * 8;
                int v0 = imax2(imax2(acc[ph][0][g], acc[ph][0][g ^ 1]),
                               imax2(acc[ph][0][g ^ 4], acc[ph][0][(g ^ 4) | 1]));
                int v1 = imax2(imax2(acc[ph][1][g], acc[ph][1][g ^ 1]),
                               imax2(acc[ph][1][g ^ 4], acc[ph][1][(g ^ 4) | 1]));
                u64 bal0 = __ballot((ocA < COUT) && (fmaf((float)v0, fa0, fb0) > 0.f));
                u64 bal1 = __ballot((ocB < COUT) && (fmaf((float)v1, fa1, fb1) > 0.f));
                u64 w_lo = (bal0 & 0xffffffffull) | (bal1 << 32);
                u64 w_hi = (bal0 >> 32) | (bal1 & 0xffffffff00000000ull);
                int pyo  = ph * 2 + ((g >> 3) & 1);
                int pxo0 = (g >> 1) & 1;
                int pxo1 = pxo0 | 2;
                size_t rowb = ((size_t)b * 4 + pyo) * 4;
                if (lane == (ph * 4 + gi) * 2)
                    outp[(rowb + pxo0) * OCW + gw] = w_lo;
                else if (lane == (ph * 4 + gi) * 2 + 1)
                    outp[(rowb + pxo1) * OCW + gw] = w_hi;
            }
        } else {
#pragma unroll
            for (int reg = 0; reg < 16; ++reg) {
                u64 bal0 = __ballot((ocA < COUT) && (fmaf((float)acc[ph][0][reg], fa0, fb0) > 0.f));
                u64 bal1 = __ballot((ocB < COUT) && (fmaf((float)acc[ph][1][reg], fa1, fb1) > 0.f));
                u64 w_lo = (bal0 & 0xffffffffull) | (bal1 << 32);
                u64 w_hi = (bal0 >> 32) | (bal1 & 0xffffffff00000000ull);
                int row  = (reg & 3) + 8 * (reg >> 2);
                int p_lo = ph * 32 + row;
                int p_hi = p_lo + 4;
                if (lane == reg * 2)
                    outp[(((size_t)b * 8 + (p_lo >> 3)) * 8 + (p_lo & 7)) * OCW + gw] = w_lo;
                else if (lane == reg * 2 + 1)
                    outp[(((size_t)b * 8 + (p_hi >> 3)) * 8 + (p_hi & 7)) * OCW + gw] = w_hi;
            }
        }
    }
}

// ---------------------------------------------------------------------------
// FC: out[b][k] = 15568 - 2*popcount(a6[b] ^ wfc[k]) + fcb[k]   (exact)
// ---------------------------------------------------------------------------
__global__ void fc_kernel(const u64* __restrict__ a6, const u64* __restrict__ wfc,
                          const float* __restrict__ fcb, float* __restrict__ out)
{
    int idx = blockIdx.x * blockDim.x + threadIdx.x;
    if (idx >= 2560) return;
    int k = idx % 10, b = idx / 10;
    const u64* ap = a6 + (size_t)b * 256;
    const u64* wq = wfc + (size_t)k * 256;
    int pop = 0;
#pragma unroll 8
    for (int q = 0; q < 256; ++q) pop += __popcll(ap[q] ^ wq[q]);
    out[idx] = (float)(15568 - 2 * pop) + fcb[k];
}

// ---------------------------------------------------------------------------
// launch
// ---------------------------------------------------------------------------
extern "C" void kernel_launch(void* const* d_in, const int* in_sizes, int n_in,
                              void* d_out, int out_size, void* d_ws, size_t ws_size,
                              hipStream_t stream)
{
    const float* x   = (const float*)d_in[0];
    const float* w0  = (const float*)d_in[1];
    const float* p0  = (const float*)d_in[2];
    const float* w1  = (const float*)d_in[3];
    const float* p1  = (const float*)d_in[4];
    const float* w2  = (const float*)d_in[5];
    const float* p2  = (const float*)d_in[6];
    const float* w3  = (const float*)d_in[7];
    const float* p3  = (const float*)d_in[8];
    const float* w4  = (const float*)d_in[9];
    const float* p4  = (const float*)d_in[10];
    const float* w5  = (const float*)d_in[11];
    const float* p5  = (const float*)d_in[12];
    const float* fcw = (const float*)d_in[13];
    const float* fcb = (const float*)d_in[14];
    float* out = (float*)d_out;

    u64* WS = (u64*)d_ws;
    u64* A0 = WS;                  // [256][32][32][1]  = 262144
    u64* A1 = A0 + 262144;         // [256][32][32][6]  = 1572864
    u64* A2 = A1 + 1572864;        // [256][16][16][6]  = 393216
    u64* A3 = A2 + 393216;         // [256][16][16][11] = 720896
    u64* A4 = A3 + 720896;         // [256][8][8][11]   = 180224
    u64* A5 = A4 + 180224;         // [256][8][8][20]   = 327680
    u64* A6 = A5 + 327680;         // [256][4][4][16]   = 65536
    u64* WFp = A6 + 65536;         // 2560
    char* WB0 = (char*)(WFp + 2560);   //   221,184 (KC=2,  OCG=12)
    char* WB1 = WB0 + 221184;          // 1,327,104 (KC=12, OCG=12)
    char* WB2 = WB1 + 1327104;         // 2,654,208 (KC=12, OCG=24)
    char* WB3 = WB2 + 2654208;         // 4,866,048 (KC=22, OCG=24)
    char* WB4 = WB3 + 4866048;         // 8,110,080 (KC=22, OCG=40)
    char* WB5 = WB4 + 8110080;         // 11,796,480 (KC=40, OCG=32)
    float* SA0 = (float*)(WB5 + 11796480);
    float* SB0 = SA0 + 1280;
    float* SA1 = SB0 + 1280;
    float* SB1 = SA1 + 1280;
    float* SA2 = SB1 + 1280;
    float* SB2 = SA2 + 1280;
    float* SA3 = SB2 + 1280;
    float* SB3 = SA3 + 1280;
    float* SA4 = SB3 + 1280;
    float* SB4 = SA4 + 1280;
    float* SA5 = SB4 + 1280;
    float* SB5 = SA5 + 1280;
    // total ws: ~57.2 MB

    pack_input_kernel<<<1024, 256, 0, stream>>>(x, A0);
    pack_w_i8<<<(9 * 2 * 12 * 64 + 255) / 256, 256, 0, stream>>>(w0, WB0, 344, 3, 2, 12);
    pack_w_i8<<<(9 * 12 * 12 * 64 + 255) / 256, 256, 0, stream>>>(w1, WB1, 352, 344, 12, 12);
    pack_w_i8<<<(9 * 12 * 24 * 64 + 255) / 256, 256, 0, stream>>>(w2, WB2, 686, 352, 12, 24);
    pack_w_i8<<<(9 * 22 * 24 * 64 + 255) / 256, 256, 0, stream>>>(w3, WB3, 679, 686, 22, 24);
    pack_w_i8<<<(9 * 22 * 40 * 64 + 255) / 256, 256, 0, stream>>>(w4, WB4, 1246, 679, 22, 40);
    pack_w_i8<<<(9 * 40 * 32 * 64 + 255) / 256, 256, 0, stream>>>(w5, WB5, 973, 1246, 40, 32);
    pack_bn_kernel<<<2, 256, 0, stream>>>(p0, SA0, SB0, 344);
    pack_bn_kernel<<<2, 256, 0, stream>>>(p1, SA1, SB1, 352);
    pack_bn_kernel<<<3, 256, 0, stream>>>(p2, SA2, SB2, 686);
    pack_bn_kernel<<<3, 256, 0, stream>>>(p3, SA3, SB3, 679);
    pack_bn_kernel<<<5, 256, 0, stream>>>(p4, SA4, SB4, 1246);
    pack_bn_kernel<<<4, 256, 0, stream>>>(p5, SA5, SB5, 973);
    pack_fc_kernel<<<10, 256, 0, stream>>>(fcw, WFp);

    // conv layers
    conv_mfma16<32, 32,  1, 12,  6, 344, false>
        <<<dim3(1024, 3), 256, 0, stream>>>(A0, (const v4i*)WB0, SA0, SB0, A1);
    conv_mfma16<32, 32,  6, 12,  6, 352, true>
        <<<dim3(1024, 3), 256, 0, stream>>>(A1, (const v4i*)WB1, SA1, SB1, A2);
    conv_mfma16<16, 16,  6, 24, 11, 686, false>
        <<<dim3(256, 6), 256, 0, stream>>>(A2, (const v4i*)WB2, SA2, SB2, A3);
    conv_mfma16<16, 16, 11, 24, 11, 679, true>
        <<<dim3(256, 6), 256, 0, stream>>>(A3, (const v4i*)WB3, SA3, SB3, A4);
    conv_mfma8<11, 40, 20, 1246, false>
        <<<dim3(64, 20), 256, 0, stream>>>(A4, (const v4i*)WB4, SA4, SB4, A5);
    conv_mfma8<20, 32, 16, 973, true>
        <<<dim3(64, 16), 256, 0, stream>>>(A5, (const v4i*)WB5, SA5, SB5, A6);

    fc_kernel<<<10, 256, 0, stream>>>(A6, WFp, fcb, out);
}

// Round 6
// 1372.706 us; speedup vs baseline: 2.5272x; 1.0793x over previous
//
#include <hip/hip_runtime.h>
#include <stdint.h>

typedef unsigned long long u64;
typedef int v4i  __attribute__((ext_vector_type(4)));
typedef int v16i __attribute__((ext_vector_type(16)));

static __device__ __forceinline__ v16i mfma_i8(v4i a, v4i b, v16i c) {
    return __builtin_amdgcn_mfma_i32_32x32x32_i8(a, b, c, 0, 0, 0);
}
static __device__ __forceinline__ int imax2(int a, int b) { return a > b ? a : b; }

static __device__ __forceinline__ void gload_lds16(const void* g, void* l) {
    __builtin_amdgcn_global_load_lds(
        (const __attribute__((address_space(1))) unsigned int*)g,
        (__attribute__((address_space(3))) unsigned int*)l, 16, 0, 0);
}

// ---------------------------------------------------------------------------
// Pack input x [256,3,32,32] f32 -> A0 [256][32][32][1] u64 (bits 0..2 = sign>0)
// ---------------------------------------------------------------------------
__global__ void pack_input_kernel(const float* __restrict__ x, u64* __restrict__ a0)
{
    int idx = blockIdx.x * blockDim.x + threadIdx.x;
    if (idx >= 256 * 1024) return;
    int b = idx >> 10, pix = idx & 1023;
    const float* xp = x + (size_t)b * 3072 + pix;
    u64 wd = 0;
    if (xp[0]    > 0.f) wd |= 1ull;
    if (xp[1024] > 0.f) wd |= 2ull;
    if (xp[2048] > 0.f) wd |= 4ull;
    a0[idx] = wd;
}

// ---------------------------------------------------------------------------
// w [O][C][3][3] f32 -> B-fragment i8 slab:
//   v4i index = ((t*KC + kc)*OCG + og)*64 + lane ; byte j of that v4i:
//   oc = og*32 + (lane&31), c = kc*32 + (lane>>5)*16 + j ; 0 if oc>=O or c>=C
// ---------------------------------------------------------------------------
__global__ void pack_w_i8(const float* __restrict__ w, char* __restrict__ wb,
                          int O, int C, int KC, int OCG)
{
    int idx = blockIdx.x * blockDim.x + threadIdx.x;
    int total = 9 * KC * OCG * 64;
    if (idx >= total) return;
    int lane = idx & 63;
    int rest = idx >> 6;
    int og = rest % OCG; rest /= OCG;
    int kc = rest % KC;  int t = rest / KC;
    int oc = og * 32 + (lane & 31);
    int cb = kc * 32 + (lane >> 5) * 16;
    char vals[16];
#pragma unroll
    for (int j = 0; j < 16; ++j) {
        int c = cb + j;
        char v = 0;
        if (oc < O && c < C)
            v = (w[(size_t)(oc * C + c) * 9 + t] > 0.f) ? (char)1 : (char)-1;
        vals[j] = v;
    }
    *(v4i*)(wb + (size_t)idx * 16) = *(v4i*)vals;
}

// ---------------------------------------------------------------------------
// BN -> (scale, offset): bn(y) = y*sa + sb
// ---------------------------------------------------------------------------
__global__ void pack_bn_kernel(const float* __restrict__ p, float* __restrict__ sa,
                               float* __restrict__ sb, int C)
{
    int i = blockIdx.x * blockDim.x + threadIdx.x;
    if (i >= C) return;
    float g = p[i], b = p[C + i], m = p[2 * C + i], v = p[3 * C + i];
    float s = g * rsqrtf(v + 1e-5f);
    sa[i] = s;
    sb[i] = fmaf(-m, s, b);
}

// ---------------------------------------------------------------------------
// Pack fc weights [10][15568] f32 -> [10][16 pix][16 words] u64
// ---------------------------------------------------------------------------
__global__ void pack_fc_kernel(const float* __restrict__ fcw, u64* __restrict__ wfc)
{
    int idx = blockIdx.x * blockDim.x + threadIdx.x;
    if (idx >= 10 * 256) return;
    int w = idx & 15;
    int p = (idx >> 4) & 15;
    int k = idx >> 8;
    u64 word = 0;
    for (int c2 = 0; c2 < 64; ++c2) {
        int c = w * 64 + c2;
        if (c < 973) {
            if (fcw[(size_t)k * 15568 + c * 16 + p] > 0.f) word |= (1ull << c2);
        }
    }
    wfc[idx] = word;
}

// ---------------------------------------------------------------------------
// unpack helper: 16 sign bits -> 4 planes of 4 bytes (+1/-1), halo -> 0
// ---------------------------------------------------------------------------
static __device__ __forceinline__ int unpack4(unsigned hw, int q) {
    unsigned nib = (hw >> (4 * q)) & 0xfu;
    unsigned spread = (nib * 0x00204081u) & 0x01010101u;   // u24 mul
    return (int)(0xffffffffu ^ ((spread << 8) - (spread << 1)));
}

// ---------------------------------------------------------------------------
// v6 conv: block = 4 waves = 512 px x 64 oc (one ocg pair, = one u64 out word).
// Wave = 128 px (4 ag groups) x 64 oc -> acc[4][2]. Per K-chunk: stage A
// (unpacked bit->i8 planes) AND B (async global_load_lds, layout-identical)
// into LDS; K-loop is pure ds_read_b128 (immediate offsets) + MFMA.
// LDS: [B 36KB][A 4 planes]. Tile: NIMG images of TH x TW (NIMG*TH*TW=512).
// ---------------------------------------------------------------------------
template <int H, int W, int TH, int TW, int NIMG, int KWIN, int OCG_T, int OCW,
          int COUT, bool POOL>
__global__ __launch_bounds__(256, 2)
void conv_v6(const u64* __restrict__ act, const char* __restrict__ wb,
             const float* __restrict__ sA, const float* __restrict__ sB,
             u64* __restrict__ outp)
{
    constexpr int KC = 2 * KWIN;
    constexpr int CW = TW + 2;
    constexpr int CELLS_I = (TH + 2) * CW;
    constexpr int CELLS = NIMG * CELLS_I;
    constexpr int PLANE = CELLS * 16;
    constexpr int BSZ = 36864;              // 36 units x 1KB
    __shared__ __attribute__((aligned(16))) char smem[BSZ + 4 * PLANE];

    const int tid  = threadIdx.x;
    const int lane = tid & 63;
    const int wm   = tid >> 6;
    const int half = lane >> 5;
    const int m    = lane & 31;

    int b0i, y0;
    if constexpr (NIMG == 1) {
        b0i = blockIdx.x >> 1;
        y0 = (blockIdx.x & 1) * TH;
    } else {
        b0i = blockIdx.x * NIMG;
        y0 = 0;
    }

    const int ocg0 = blockIdx.y * 2;
    const int gw   = blockIdx.y;

    int aoff[4];
#pragma unroll
    for (int ag = 0; ag < 4; ++ag) {
        int p = wm * 128 + ag * 32 + m;
        int img = p / (TH * TW);
        int pp = p % (TH * TW);
        aoff[ag] = ((img * CELLS_I + (pp / TW) * CW + (pp % TW)) << 4) + half * PLANE;
    }

    v16i acc[4][2];
#pragma unroll
    for (int ag = 0; ag < 4; ++ag)
#pragma unroll
        for (int o = 0; o < 2; ++o)
#pragma unroll
            for (int i = 0; i < 16; ++i) acc[ag][o][i] = 0;

#pragma unroll 1
    for (int c64 = 0; c64 < KWIN; ++c64) {
        // ---- B stage: 36 x 1KB units via async global->LDS DMA ----
        for (int u = wm; u < 36; u += 4) {
            int og = u & 1, tks = u >> 1;
            int t = tks >> 1, ks = tks & 1;
            const char* gp = wb + ((size_t)((t * KC + c64 * 2 + ks) * OCG_T + ocg0 + og)) * 1024
                             + lane * 16;
            gload_lds16(gp, smem + u * 1024);
        }
        // ---- A stage: unpack bit-words into 4 i8 planes ----
        for (int cell = tid; cell < CELLS; cell += 256) {
            int img, c2;
            if constexpr (NIMG == 1) { img = 0; c2 = cell; }
            else { img = cell / CELLS_I; c2 = cell % CELLS_I; }
            int cy = c2 / CW, cx = c2 % CW;
            int gy = y0 + cy - 1, gx = cx - 1;
            char* dst = smem + BSZ + cell * 16;
            if ((unsigned)gy < (unsigned)H && (unsigned)gx < (unsigned)W) {
                u64 wd = act[((size_t)(b0i + img) * H * W + (size_t)gy * W + gx) * KWIN + c64];
                unsigned hv[4];
                hv[0] = (unsigned)wd & 0xffffu;
                hv[1] = ((unsigned)wd) >> 16;
                hv[2] = (unsigned)(wd >> 32) & 0xffffu;
                hv[3] = (unsigned)(wd >> 48);
#pragma unroll
                for (int s = 0; s < 4; ++s) {
                    v4i v;
#pragma unroll
                    for (int q = 0; q < 4; ++q) v[q] = unpack4(hv[s], q);
                    *(v4i*)(dst + s * PLANE) = v;
                }
            } else {
                v4i z = {0, 0, 0, 0};
#pragma unroll
                for (int s = 0; s < 4; ++s) *(v4i*)(dst + s * PLANE) = z;
            }
        }
        __syncthreads();   // drains DMA (vmcnt) + LDS writes

        // ---- K-steps: pure LDS -> MFMA, all offsets immediate ----
#pragma unroll
        for (int s = 0; s < 18; ++s) {
            const int t = s >> 1, ks = s & 1;
            const int aimm = BSZ + ks * 2 * PLANE + (((t / 3) * CW) + (t % 3)) * 16;
            v4i b0 = *(const v4i*)(smem + (s * 2 + 0) * 1024 + lane * 16);
            v4i b1 = *(const v4i*)(smem + (s * 2 + 1) * 1024 + lane * 16);
            v4i a0 = *(const v4i*)(smem + aoff[0] + aimm);
            v4i a1 = *(const v4i*)(smem + aoff[1] + aimm);
            v4i a2 = *(const v4i*)(smem + aoff[2] + aimm);
            v4i a3 = *(const v4i*)(smem + aoff[3] + aimm);
            acc[0][0] = mfma_i8(a0, b0, acc[0][0]);
            acc[1][0] = mfma_i8(a1, b0, acc[1][0]);
            acc[2][0] = mfma_i8(a2, b0, acc[2][0]);
            acc[3][0] = mfma_i8(a3, b0, acc[3][0]);
            acc[0][1] = mfma_i8(a0, b1, acc[0][1]);
            acc[1][1] = mfma_i8(a1, b1, acc[1][1]);
            acc[2][1] = mfma_i8(a2, b1, acc[2][1]);
            acc[3][1] = mfma_i8(a3, b1, acc[3][1]);
        }
        __syncthreads();
    }

    // ---- epilogue: (pool) + BN-sign -> ballot-packed u64 stores ----
    const int ocA = ocg0 * 32 + m;
    const int ocB = ocA + 32;
    const float fa0 = sA[ocA < COUT ? ocA : 0], fb0 = sB[ocA < COUT ? ocA : 0];
    const float fa1 = sA[ocB < COUT ? ocB : 0], fb1 = sB[ocB < COUT ? ocB : 0];

#pragma unroll
    for (int ag = 0; ag < 4; ++ag) {
        if constexpr (POOL && TW == 32) {
            if (ag & 1) continue;   // vertical pool pairs rows (ag, ag+1)
#pragma unroll
            for (int gi = 0; gi < 8; ++gi) {
                const int g = gi * 2;
                int v0 = imax2(imax2(acc[ag][0][g], acc[ag][0][g ^ 1]),
                               imax2(acc[ag + 1][0][g], acc[ag + 1][0][g ^ 1]));
                int v1 = imax2(imax2(acc[ag][1][g], acc[ag][1][g ^ 1]),
                               imax2(acc[ag + 1][1][g], acc[ag + 1][1][g ^ 1]));
                u64 bal0 = __ballot((ocA < COUT) && (fmaf((float)v0, fa0, fb0) > 0.f));
                u64 bal1 = __ballot((ocB < COUT) && (fmaf((float)v1, fa1, fb1) > 0.f));
                u64 w_lo = (bal0 & 0xffffffffull) | (bal1 << 32);
                u64 w_hi = (bal0 >> 32) | (bal1 & 0xffffffff00000000ull);
                int pyo  = wm * 2 + (ag >> 1);
                int pxo0 = ((g & 3) >> 1) + 4 * (g >> 2);
                size_t rowb = ((size_t)b0i * (H / 2) + (y0 / 2 + pyo)) * (W / 2);
                if (lane == (ag >> 1) * 16 + gi * 2)
                    outp[(rowb + pxo0) * OCW + gw] = w_lo;
                else if (lane == (ag >> 1) * 16 + gi * 2 + 1)
                    outp[(rowb + pxo0 + 2) * OCW + gw] = w_hi;
            }
        } else if constexpr (POOL) {   // TW == 16, NIMG images
#pragma unroll
            for (int gi = 0; gi < 4; ++gi) {
                const int g = gi * 2;   // {0,2,4,6}
                int v0 = imax2(imax2(acc[ag][0][g], acc[ag][0][g ^ 1]),
                               imax2(acc[ag][0][g ^ 8], acc[ag][0][(g ^ 8) | 1]));
                int v1 = imax2(imax2(acc[ag][1][g], acc[ag][1][g ^ 1]),
                               imax2(acc[ag][1][g ^ 8], acc[ag][1][(g ^ 8) | 1]));
                u64 bal0 = __ballot((ocA < COUT) && (fmaf((float)v0, fa0, fb0) > 0.f));
                u64 bal1 = __ballot((ocB < COUT) && (fmaf((float)v1, fa1, fb1) > 0.f));
                u64 w_lo = (bal0 & 0xffffffffull) | (bal1 << 32);
                u64 w_hi = (bal0 >> 32) | (bal1 & 0xffffffff00000000ull);
                int img  = wm >> 1;
                int pyo  = (wm & 1) * 4 + ag;
                int pxo0 = ((g >> 1) & 1) | (((g >> 2) & 1) << 2);
                size_t rowb = ((size_t)(b0i + img) * (TH / 2) + pyo) * (TW / 2);
                if (lane == (ag * 4 + gi) * 2)
                    outp[(rowb + pxo0) * OCW + gw] = w_lo;
                else if (lane == (ag * 4 + gi) * 2 + 1)
                    outp[(rowb + pxo0 + 2) * OCW + gw] = w_hi;
            }
        } else {
#pragma unroll
            for (int reg = 0; reg < 16; ++reg) {
                u64 bal0 = __ballot((ocA < COUT) && (fmaf((float)acc[ag][0][reg], fa0, fb0) > 0.f));
                u64 bal1 = __ballot((ocB < COUT) && (fmaf((float)acc[ag][1][reg], fa1, fb1) > 0.f));
                u64 w_lo = (bal0 & 0xffffffffull) | (bal1 << 32);
                u64 w_hi = (bal0 >> 32) | (bal1 & 0xffffffff00000000ull);
                int row  = (reg & 3) + 8 * (reg >> 2);
                int p_lo = wm * 128 + ag * 32 + row;
                int p_hi = p_lo + 4;
                if (lane == reg * 2) {
                    int img, py, px;
                    if constexpr (TW == 32) { img = 0; py = p_lo >> 5; px = p_lo & 31; }
                    else { img = p_lo >> 8; py = (p_lo >> 4) & 15; px = p_lo & 15; }
                    outp[(((size_t)(b0i + img) * H + (y0 + py)) * W + px) * OCW + gw] = w_lo;
                } else if (lane == reg * 2 + 1) {
                    int img, py, px;
                    if constexpr (TW == 32) { img = 0; py = p_hi >> 5; px = p_hi & 31; }
                    else { img = p_hi >> 8; py = (p_hi >> 4) & 15; px = p_hi & 15; }
                    outp[(((size_t)(b0i + img) * H + (y0 + py)) * W + px) * OCW + gw] = w_hi;
                }
            }
        }
    }
}

// ---------------------------------------------------------------------------
// 8x8-layer conv (unchanged from R5, proven): block = 4 waves = 4 images x 64 oc.
// ---------------------------------------------------------------------------
template <int KWIN, int OCG, int OCW, int COUT, bool POOL>
__global__ __launch_bounds__(256, 3)
void conv_mfma8(const u64* __restrict__ act, const v4i* __restrict__ wb,
                const float* __restrict__ sA, const float* __restrict__ sB,
                u64* __restrict__ outp)
{
    constexpr int KC = 2 * KWIN;
    constexpr int CELLS = 100;
    constexpr int PLANE = CELLS * 16;
    constexpr int IMG = 4 * PLANE;
    __shared__ __attribute__((aligned(16))) char smem[4 * IMG];

    const int tid  = threadIdx.x;
    const int lane = tid & 63;
    const int wave = tid >> 6;
    const int half = lane >> 5;
    const int m    = lane & 31;

    const int b = blockIdx.x * 4 + wave;
    const int ocg0 = blockIdx.y * 2;
    const int gw = blockIdx.y;

    int aoff[2];
#pragma unroll
    for (int ph = 0; ph < 2; ++ph) {
        int p = ph * 32 + m;
        aoff[ph] = wave * IMG + ((p >> 3) * 10 + (p & 7)) * 16 + half * PLANE;
    }

    v16i acc[2][2];
#pragma unroll
    for (int a = 0; a < 2; ++a)
#pragma unroll
        for (int o = 0; o < 2; ++o)
#pragma unroll
            for (int i = 0; i < 16; ++i) acc[a][o][i] = 0;

    const u64* actb = act + (size_t)b * (64 * KWIN);

    v4i b0n, b1n;
    {
        const v4i* pn = wb + ((size_t)ocg0) * 64 + lane;
        b0n = pn[0]; b1n = pn[64];
    }

#pragma unroll 1
    for (int c64 = 0; c64 < KWIN; ++c64) {
        for (int cell = lane; cell < CELLS; cell += 64) {
            int cy = cell / 10, cx = cell % 10;
            int gy = cy - 1, gx = cx - 1;
            char* dst = smem + wave * IMG + cell * 16;
            if ((unsigned)gy < 8u && (unsigned)gx < 8u) {
                u64 wd = actb[((size_t)gy * 8 + gx) * KWIN + c64];
                unsigned hv[4];
                hv[0] = (unsigned)wd & 0xffffu;
                hv[1] = ((unsigned)wd) >> 16;
                hv[2] = (unsigned)(wd >> 32) & 0xffffu;
                hv[3] = (unsigned)(wd >> 48);
#pragma unroll
                for (int s = 0; s < 4; ++s) {
                    v4i v;
#pragma unroll
                    for (int q = 0; q < 4; ++q) v[q] = unpack4(hv[s], q);
                    *(v4i*)(dst + s * PLANE) = v;
                }
            } else {
                v4i z = {0, 0, 0, 0};
#pragma unroll
                for (int s = 0; s < 4; ++s) *(v4i*)(dst + s * PLANE) = z;
            }
        }
        __syncthreads();

#pragma unroll
        for (int s = 0; s < 18; ++s) {
            v4i b0 = b0n, b1 = b1n;
            {
                const int sn = (s + 1) % 18;
                const int cn = (s == 17) ? (c64 + 1) : c64;
                const v4i* pn = wb + ((size_t)(((sn >> 1) * KC + cn * 2 + (sn & 1)) * OCG + ocg0)) * 64 + lane;
                b0n = pn[0]; b1n = pn[64];
            }
            const int t = s >> 1, ks = s & 1;
            const int toff = ((t / 3) * 10 + (t % 3)) * 16 + ks * (2 * PLANE);
            v4i a0 = *(const v4i*)(smem + aoff[0] + toff);
            v4i a1 = *(const v4i*)(smem + aoff[1] + toff);
            acc[0][0] = mfma_i8(a0, b0, acc[0][0]);
            acc[1][0] = mfma_i8(a1, b0, acc[1][0]);
            acc[0][1] = mfma_i8(a0, b1, acc[0][1]);
            acc[1][1] = mfma_i8(a1, b1, acc[1][1]);
        }
        __syncthreads();
    }

    const int ocA = ocg0 * 32 + m;
    const int ocB = ocA + 32;
    const float fa0 = sA[ocA < COUT ? ocA : 0], fb0 = sB[ocA < COUT ? ocA : 0];
    const float fa1 = sA[ocB < COUT ? ocB : 0], fb1 = sB[ocB < COUT ? ocB : 0];

#pragma unroll
    for (int ph = 0; ph < 2; ++ph) {
        if constexpr (POOL) {
#pragma unroll
            for (int gi = 0; gi < 4; ++gi) {
                const int g = (gi & 1) * 2 + (gi >> 1) * 8;
                int v0 = imax2(imax2(acc[ph][0][g], acc[ph][0][g ^ 1]),
                               imax2(acc[ph][0][g ^ 4], acc[ph][0][(g ^ 4) | 1]));
                int v1 = imax2(imax2(acc[ph][1][g], acc[ph][1][g ^ 1]),
                               imax2(acc[ph][1][g ^ 4], acc[ph][1][(g ^ 4) | 1]));
                u64 bal0 = __ballot((ocA < COUT) && (fmaf((float)v0, fa0, fb0) > 0.f));
                u64 bal1 = __ballot((ocB < COUT) && (fmaf((float)v1, fa1, fb1) > 0.f));
                u64 w_lo = (bal0 & 0xffffffffull) | (bal1 << 32);
                u64 w_hi = (bal0 >> 32) | (bal1 & 0xffffffff00000000ull);
                int pyo  = ph * 2 + ((g >> 3) & 1);
                int pxo0 = (g >> 1) & 1;
                int pxo1 = pxo0 | 2;
                size_t rowb = ((size_t)b * 4 + pyo) * 4;
                if (lane == (ph * 4 + gi) * 2)
                    outp[(rowb + pxo0) * OCW + gw] = w_lo;
                else if (lane == (ph * 4 + gi) * 2 + 1)
                    outp[(rowb + pxo1) * OCW + gw] = w_hi;
            }
        } else {
#pragma unroll
            for (int reg = 0; reg < 16; ++reg) {
                u64 bal0 = __ballot((ocA < COUT) && (fmaf((float)acc[ph][0][reg], fa0, fb0) > 0.f));
                u64 bal1 = __ballot((ocB < COUT) && (fmaf((float)acc[ph][1][reg], fa1, fb1) > 0.f));
                u64 w_lo = (bal0 & 0xffffffffull) | (bal1 << 32);
                u64 w_hi = (bal0 >> 32) | (bal1 & 0xffffffff00000000ull);
                int row  = (reg & 3) + 8 * (reg >> 2);
                int p_lo = ph * 32 + row;
                int p_hi = p_lo + 4;
                if (lane == reg * 2)
                    outp[(((size_t)b * 8 + (p_lo >> 3)) * 8 + (p_lo & 7)) * OCW + gw] = w_lo;
                else if (lane == reg * 2 + 1)
                    outp[(((size_t)b * 8 + (p_hi >> 3)) * 8 + (p_hi & 7)) * OCW + gw] = w_hi;
            }
        }
    }
}

// ---------------------------------------------------------------------------
// FC: out[b][k] = 15568 - 2*popcount(a6[b] ^ wfc[k]) + fcb[k]   (exact)
// ---------------------------------------------------------------------------
__global__ void fc_kernel(const u64* __restrict__ a6, const u64* __restrict__ wfc,
                          const float* __restrict__ fcb, float* __restrict__ out)
{
    int idx = blockIdx.x * blockDim.x + threadIdx.x;
    if (idx >= 2560) return;
    int k = idx % 10, b = idx / 10;
    const u64* ap = a6 + (size_t)b * 256;
    const u64* wq = wfc + (size_t)k * 256;
    int pop = 0;
#pragma unroll 8
    for (int q = 0; q < 256; ++q) pop += __popcll(ap[q] ^ wq[q]);
    out[idx] = (float)(15568 - 2 * pop) + fcb[k];
}

// ---------------------------------------------------------------------------
// launch
// ---------------------------------------------------------------------------
extern "C" void kernel_launch(void* const* d_in, const int* in_sizes, int n_in,
                              void* d_out, int out_size, void* d_ws, size_t ws_size,
                              hipStream_t stream)
{
    const float* x   = (const float*)d_in[0];
    const float* w0  = (const float*)d_in[1];
    const float* p0  = (const float*)d_in[2];
    const float* w1  = (const float*)d_in[3];
    const float* p1  = (const float*)d_in[4];
    const float* w2  = (const float*)d_in[5];
    const float* p2  = (const float*)d_in[6];
    const float* w3  = (const float*)d_in[7];
    const float* p3  = (const float*)d_in[8];
    const float* w4  = (const float*)d_in[9];
    const float* p4  = (const float*)d_in[10];
    const float* w5  = (const float*)d_in[11];
    const float* p5  = (const float*)d_in[12];
    const float* fcw = (const float*)d_in[13];
    const float* fcb = (const float*)d_in[14];
    float* out = (float*)d_out;

    u64* WS = (u64*)d_ws;
    u64* A0 = WS;                  // [256][32][32][1]  = 262144
    u64* A1 = A0 + 262144;         // [256][32][32][6]  = 1572864
    u64* A2 = A1 + 1572864;        // [256][16][16][6]  = 393216
    u64* A3 = A2 + 393216;         // [256][16][16][11] = 720896
    u64* A4 = A3 + 720896;         // [256][8][8][11]   = 180224
    u64* A5 = A4 + 180224;         // [256][8][8][20]   = 327680
    u64* A6 = A5 + 327680;         // [256][4][4][16]   = 65536
    u64* WFp = A6 + 65536;         // 2560
    char* WB0 = (char*)(WFp + 2560);   //   221,184 (KC=2,  OCG=12)
    char* WB1 = WB0 + 221184;          // 1,327,104 (KC=12, OCG=12)
    char* WB2 = WB1 + 1327104;         // 2,654,208 (KC=12, OCG=24)
    char* WB3 = WB2 + 2654208;         // 4,866,048 (KC=22, OCG=24)
    char* WB4 = WB3 + 4866048;         // 8,110,080 (KC=22, OCG=40)
    char* WB5 = WB4 + 8110080;         // 11,796,480 (KC=40, OCG=32)
    float* SA0 = (float*)(WB5 + 11796480);
    float* SB0 = SA0 + 1280;
    float* SA1 = SB0 + 1280;
    float* SB1 = SA1 + 1280;
    float* SA2 = SB1 + 1280;
    float* SB2 = SA2 + 1280;
    float* SA3 = SB2 + 1280;
    float* SB3 = SA3 + 1280;
    float* SA4 = SB3 + 1280;
    float* SB4 = SA4 + 1280;
    float* SA5 = SB4 + 1280;
    float* SB5 = SA5 + 1280;
    // total ws: ~57.2 MB

    pack_input_kernel<<<1024, 256, 0, stream>>>(x, A0);
    pack_w_i8<<<(9 * 2 * 12 * 64 + 255) / 256, 256, 0, stream>>>(w0, WB0, 344, 3, 2, 12);
    pack_w_i8<<<(9 * 12 * 12 * 64 + 255) / 256, 256, 0, stream>>>(w1, WB1, 352, 344, 12, 12);
    pack_w_i8<<<(9 * 12 * 24 * 64 + 255) / 256, 256, 0, stream>>>(w2, WB2, 686, 352, 12, 24);
    pack_w_i8<<<(9 * 22 * 24 * 64 + 255) / 256, 256, 0, stream>>>(w3, WB3, 679, 686, 22, 24);
    pack_w_i8<<<(9 * 22 * 40 * 64 + 255) / 256, 256, 0, stream>>>(w4, WB4, 1246, 679, 22, 40);
    pack_w_i8<<<(9 * 40 * 32 * 64 + 255) / 256, 256, 0, stream>>>(w5, WB5, 973, 1246, 40, 32);
    pack_bn_kernel<<<2, 256, 0, stream>>>(p0, SA0, SB0, 344);
    pack_bn_kernel<<<2, 256, 0, stream>>>(p1, SA1, SB1, 352);
    pack_bn_kernel<<<3, 256, 0, stream>>>(p2, SA2, SB2, 686);
    pack_bn_kernel<<<3, 256, 0, stream>>>(p3, SA3, SB3, 679);
    pack_bn_kernel<<<5, 256, 0, stream>>>(p4, SA4, SB4, 1246);
    pack_bn_kernel<<<4, 256, 0, stream>>>(p5, SA5, SB5, 973);
    pack_fc_kernel<<<10, 256, 0, stream>>>(fcw, WFp);

    // conv layers: conv_v6<H,W,TH,TW,NIMG,KWIN,OCG_T,OCW,COUT,POOL>
    conv_v6<32, 32, 16, 32, 1,  1, 12,  6, 344, false>
        <<<dim3(512, 6), 256, 0, stream>>>(A0, WB0, SA0, SB0, A1);
    conv_v6<32, 32, 16, 32, 1,  6, 12,  6, 352, true>
        <<<dim3(512, 6), 256, 0, stream>>>(A1, WB1, SA1, SB1, A2);
    conv_v6<16, 16, 16, 16, 2,  6, 24, 11, 686, false>
        <<<dim3(128, 11), 256, 0, stream>>>(A2, WB2, SA2, SB2, A3);
    conv_v6<16, 16, 16, 16, 2, 11, 24, 11, 679, true>
        <<<dim3(128, 11), 256, 0, stream>>>(A3, WB3, SA3, SB3, A4);
    conv_mfma8<11, 40, 20, 1246, false>
        <<<dim3(64, 20), 256, 0, stream>>>(A4, (const v4i*)WB4, SA4, SB4, A5);
    conv_mfma8<20, 32, 16, 973, true>
        <<<dim3(64, 16), 256, 0, stream>>>(A5, (const v4i*)WB5, SA5, SB5, A6);

    fc_kernel<<<10, 256, 0, stream>>>(A6, WFp, fcb, out);
}

// Round 7
// 912.634 us; speedup vs baseline: 3.8012x; 1.5041x over previous
//
#include <hip/hip_runtime.h>
#include <stdint.h>

typedef unsigned long long u64;
typedef int v4i  __attribute__((ext_vector_type(4)));
typedef int v8i  __attribute__((ext_vector_type(8)));
typedef float v16f __attribute__((ext_vector_type(16)));

// MX-fp4 MFMA, scales = 1.0 (E8M0 127 in every byte), fmt 4 = FP4 for A and B.
// Data duplicated into both halves of the 8-reg operand to be robust to the
// fp4 register-placement convention ([0:3] vs [4:7]).
static __device__ __forceinline__ v16f mfma_fp4(v4i a, v4i b, v16f c) {
    v8i A, B;
    A[0] = a[0]; A[1] = a[1]; A[2] = a[2]; A[3] = a[3];
    A[4] = a[0]; A[5] = a[1]; A[6] = a[2]; A[7] = a[3];
    B[0] = b[0]; B[1] = b[1]; B[2] = b[2]; B[3] = b[3];
    B[4] = b[0]; B[5] = b[1]; B[6] = b[2]; B[7] = b[3];
    return __builtin_amdgcn_mfma_scale_f32_32x32x64_f8f6f4(
        A, B, c, 4, 4, 0, 0x7F7F7F7F, 0, 0x7F7F7F7F);
}

static __device__ __forceinline__ void gload_lds16(const void* g, void* l) {
    __builtin_amdgcn_global_load_lds(
        (const __attribute__((address_space(1))) unsigned int*)g,
        (__attribute__((address_space(3))) unsigned int*)l, 16, 0, 0);
}

// ---------------------------------------------------------------------------
// Pack input x [256,3,32,32] f32 -> A0 [256][32][32][1] u64 (bits 0..2 = sign>0)
// ---------------------------------------------------------------------------
__global__ void pack_input_kernel(const float* __restrict__ x, u64* __restrict__ a0)
{
    int idx = blockIdx.x * blockDim.x + threadIdx.x;
    if (idx >= 256 * 1024) return;
    int b = idx >> 10, pix = idx & 1023;
    const float* xp = x + (size_t)b * 3072 + pix;
    u64 wd = 0;
    if (xp[0]    > 0.f) wd |= 1ull;
    if (xp[1024] > 0.f) wd |= 2ull;
    if (xp[2048] > 0.f) wd |= 4ull;
    a0[idx] = wd;
}

// ---------------------------------------------------------------------------
// w [O][C][3][3] f32 -> fp4 B-fragment slab:
//   unit = (t*KWIN + c64)*OCG + og, 1024 B each (64 lanes x 16 B).
//   lane: oc = og*32 + (lane&31), K-half h = lane>>5.
//   dword d, nibble j  <->  channel c = c64*64 + h*32 + d*8 + ((j>>1)+(j&1)*4)
//   (same permuted channel rule as the activation unpack -> contraction exact)
//   nibble: +1 -> 0x2, -1 -> 0xA, invalid channel/oc -> 0x0.
// ---------------------------------------------------------------------------
__global__ void pack_w_fp4(const float* __restrict__ w, unsigned* __restrict__ wb,
                           int O, int C, int KWIN, int OCG)
{
    int idx = blockIdx.x * blockDim.x + threadIdx.x;
    int total = 9 * KWIN * OCG * 64;
    if (idx >= total) return;
    int lane = idx & 63;
    int rest = idx >> 6;
    int og = rest % OCG; rest /= OCG;
    int c64 = rest % KWIN; int t = rest / KWIN;
    int oc = og * 32 + (lane & 31);
    int h = lane >> 5;
    unsigned out[4];
#pragma unroll
    for (int d = 0; d < 4; ++d) {
        unsigned dw = 0;
#pragma unroll
        for (int j = 0; j < 8; ++j) {
            int c = c64 * 64 + h * 32 + d * 8 + ((j >> 1) + (j & 1) * 4);
            unsigned nib = 0;
            if (oc < O && c < C)
                nib = (w[(size_t)(oc * C + c) * 9 + t] > 0.f) ? 0x2u : 0xAu;
            dw |= nib << (4 * j);
        }
        out[d] = dw;
    }
    *(v4i*)(wb + (size_t)idx * 4) = *(v4i*)out;
}

// ---------------------------------------------------------------------------
// BN -> (scale, offset): bn(y) = y*sa + sb
// ---------------------------------------------------------------------------
__global__ void pack_bn_kernel(const float* __restrict__ p, float* __restrict__ sa,
                               float* __restrict__ sb, int C)
{
    int i = blockIdx.x * blockDim.x + threadIdx.x;
    if (i >= C) return;
    float g = p[i], b = p[C + i], m = p[2 * C + i], v = p[3 * C + i];
    float s = g * rsqrtf(v + 1e-5f);
    sa[i] = s;
    sb[i] = fmaf(-m, s, b);
}

// ---------------------------------------------------------------------------
// Pack fc weights [10][15568] f32 -> [10][16 pix][16 words] u64
// ---------------------------------------------------------------------------
__global__ void pack_fc_kernel(const float* __restrict__ fcw, u64* __restrict__ wfc)
{
    int idx = blockIdx.x * blockDim.x + threadIdx.x;
    if (idx >= 10 * 256) return;
    int w = idx & 15;
    int p = (idx >> 4) & 15;
    int k = idx >> 8;
    u64 word = 0;
    for (int c2 = 0; c2 < 64; ++c2) {
        int c = w * 64 + c2;
        if (c < 973) {
            if (fcw[(size_t)k * 15568 + c * 16 + p] > 0.f) word |= (1ull << c2);
        }
    }
    wfc[idx] = word;
}

// ---------------------------------------------------------------------------
// 32 sign bits -> 32 fp4 nibbles (16 B), channel order d*8 + perm(j),
// perm(j) = (j>>1)+(j&1)*4 (matches pack_w_fp4). bit=1 -> 0x2 (+1), else 0xA.
// ---------------------------------------------------------------------------
static __device__ __forceinline__ v4i fp4_unpack32(unsigned wh)
{
    v4i r;
#pragma unroll
    for (int d = 0; d < 4; ++d) {
        unsigned b = (wh >> (8 * d)) & 0xffu;
        unsigned lo = ((b & 0xFu) * 0x00204081u) & 0x01010101u;
        unsigned hi = ((b >> 4)   * 0x00204081u) & 0x01010101u;
        unsigned spread = lo | (hi << 4);
        r[d] = (int)(0xAAAAAAAAu - (spread << 3));
    }
    return r;
}

// ---------------------------------------------------------------------------
// fp4 conv, big layers: block = 4 waves = 512 px x 64 oc. Wave = 128 px
// (4 ag groups) x 64 oc -> acc[4][2] v16f. Per 64-ch chunk: B staged by
// async DMA (18 KB), A unpacked bits->fp4 planes (2 x CELLS x 16 B);
// K-loop = 9 taps x (6 ds_read_b128 + 8 MFMA K=64).
// ---------------------------------------------------------------------------
template <int H, int W, int TH, int TW, int NIMG, int KWIN, int OCG_T, int OCW,
          int COUT, bool POOL>
__global__ __launch_bounds__(256, 2)
void conv_v6f(const u64* __restrict__ act, const char* __restrict__ wb,
              const float* __restrict__ sA, const float* __restrict__ sB,
              u64* __restrict__ outp)
{
    constexpr int CW = TW + 2;
    constexpr int CELLS_I = (TH + 2) * CW;
    constexpr int CELLS = NIMG * CELLS_I;
    constexpr int PLANE = CELLS * 16;
    constexpr int BSZ = 18432;              // 18 units x 1KB
    __shared__ __attribute__((aligned(16))) char smem[BSZ + 2 * PLANE];

    const int tid  = threadIdx.x;
    const int lane = tid & 63;
    const int wm   = tid >> 6;
    const int h    = lane >> 5;
    const int m    = lane & 31;

    int b0i, y0;
    if constexpr (NIMG == 1) {
        b0i = blockIdx.x >> 1;
        y0 = (blockIdx.x & 1) * TH;
    } else {
        b0i = blockIdx.x * NIMG;
        y0 = 0;
    }

    const int ocg0 = blockIdx.y * 2;
    const int gw   = blockIdx.y;

    int aoff[4];
#pragma unroll
    for (int ag = 0; ag < 4; ++ag) {
        int p = wm * 128 + ag * 32 + m;
        int img = p / (TH * TW);
        int pp = p % (TH * TW);
        aoff[ag] = ((img * CELLS_I + (pp / TW) * CW + (pp % TW)) << 4) + h * PLANE;
    }

    v16f acc[4][2];
#pragma unroll
    for (int ag = 0; ag < 4; ++ag)
#pragma unroll
        for (int o = 0; o < 2; ++o)
#pragma unroll
            for (int i = 0; i < 16; ++i) acc[ag][o][i] = 0.0f;

#pragma unroll 1
    for (int c64 = 0; c64 < KWIN; ++c64) {
        // ---- B stage: 18 x 1KB units via async global->LDS DMA ----
        for (int u = wm; u < 18; u += 4) {
            int og = u & 1, t = u >> 1;
            const char* gp = wb + ((size_t)((t * KWIN + c64) * OCG_T + ocg0 + og)) * 1024
                             + lane * 16;
            gload_lds16(gp, smem + u * 1024);
        }
        // ---- A stage: unpack bit-words into 2 fp4 planes ----
        for (int cell = tid; cell < CELLS; cell += 256) {
            int img, c2;
            if constexpr (NIMG == 1) { img = 0; c2 = cell; }
            else { img = cell / CELLS_I; c2 = cell % CELLS_I; }
            int cy = c2 / CW, cx = c2 % CW;
            int gy = y0 + cy - 1, gx = cx - 1;
            char* dst = smem + BSZ + cell * 16;
            if ((unsigned)gy < (unsigned)H && (unsigned)gx < (unsigned)W) {
                u64 wd = act[((size_t)(b0i + img) * H * W + (size_t)gy * W + gx) * KWIN + c64];
                *(v4i*)dst           = fp4_unpack32((unsigned)wd);
                *(v4i*)(dst + PLANE) = fp4_unpack32((unsigned)(wd >> 32));
            } else {
                v4i z = {0, 0, 0, 0};
                *(v4i*)dst           = z;
                *(v4i*)(dst + PLANE) = z;
            }
        }
        __syncthreads();   // drains DMA (vmcnt) + LDS writes

        // ---- K-steps: one tap = one K=64 MFMA per acc tile ----
#pragma unroll
        for (int t = 0; t < 9; ++t) {
            const int aimm = BSZ + (((t / 3) * CW) + (t % 3)) * 16;
            v4i b0 = *(const v4i*)(smem + (t * 2 + 0) * 1024 + lane * 16);
            v4i b1 = *(const v4i*)(smem + (t * 2 + 1) * 1024 + lane * 16);
            v4i a0 = *(const v4i*)(smem + aoff[0] + aimm);
            v4i a1 = *(const v4i*)(smem + aoff[1] + aimm);
            v4i a2 = *(const v4i*)(smem + aoff[2] + aimm);
            v4i a3 = *(const v4i*)(smem + aoff[3] + aimm);
            acc[0][0] = mfma_fp4(a0, b0, acc[0][0]);
            acc[1][0] = mfma_fp4(a1, b0, acc[1][0]);
            acc[2][0] = mfma_fp4(a2, b0, acc[2][0]);
            acc[3][0] = mfma_fp4(a3, b0, acc[3][0]);
            acc[0][1] = mfma_fp4(a0, b1, acc[0][1]);
            acc[1][1] = mfma_fp4(a1, b1, acc[1][1]);
            acc[2][1] = mfma_fp4(a2, b1, acc[2][1]);
            acc[3][1] = mfma_fp4(a3, b1, acc[3][1]);
        }
        __syncthreads();
    }

    // ---- epilogue: (pool) + BN-sign -> ballot-packed u64 stores ----
    const int ocA = ocg0 * 32 + m;
    const int ocB = ocA + 32;
    const float fa0 = sA[ocA < COUT ? ocA : 0], fb0 = sB[ocA < COUT ? ocA : 0];
    const float fa1 = sA[ocB < COUT ? ocB : 0], fb1 = sB[ocB < COUT ? ocB : 0];

#pragma unroll
    for (int ag = 0; ag < 4; ++ag) {
        if constexpr (POOL && TW == 32) {
            if (ag & 1) continue;   // vertical pool pairs rows (ag, ag+1)
#pragma unroll
            for (int gi = 0; gi < 8; ++gi) {
                const int g = gi * 2;
                float v0 = fmaxf(fmaxf(acc[ag][0][g], acc[ag][0][g ^ 1]),
                                 fmaxf(acc[ag + 1][0][g], acc[ag + 1][0][g ^ 1]));
                float v1 = fmaxf(fmaxf(acc[ag][1][g], acc[ag][1][g ^ 1]),
                                 fmaxf(acc[ag + 1][1][g], acc[ag + 1][1][g ^ 1]));
                u64 bal0 = __ballot((ocA < COUT) && (fmaf(v0, fa0, fb0) > 0.f));
                u64 bal1 = __ballot((ocB < COUT) && (fmaf(v1, fa1, fb1) > 0.f));
                u64 w_lo = (bal0 & 0xffffffffull) | (bal1 << 32);
                u64 w_hi = (bal0 >> 32) | (bal1 & 0xffffffff00000000ull);
                int pyo  = wm * 2 + (ag >> 1);
                int pxo0 = ((g & 3) >> 1) + 4 * (g >> 2);
                size_t rowb = ((size_t)b0i * (H / 2) + (y0 / 2 + pyo)) * (W / 2);
                if (lane == (ag >> 1) * 16 + gi * 2)
                    outp[(rowb + pxo0) * OCW + gw] = w_lo;
                else if (lane == (ag >> 1) * 16 + gi * 2 + 1)
                    outp[(rowb + pxo0 + 2) * OCW + gw] = w_hi;
            }
        } else if constexpr (POOL) {   // TW == 16, NIMG images
#pragma unroll
            for (int gi = 0; gi < 4; ++gi) {
                const int g = gi * 2;
                float v0 = fmaxf(fmaxf(acc[ag][0][g], acc[ag][0][g ^ 1]),
                                 fmaxf(acc[ag][0][g ^ 8], acc[ag][0][(g ^ 8) | 1]));
                float v1 = fmaxf(fmaxf(acc[ag][1][g], acc[ag][1][g ^ 1]),
                                 fmaxf(acc[ag][1][g ^ 8], acc[ag][1][(g ^ 8) | 1]));
                u64 bal0 = __ballot((ocA < COUT) && (fmaf(v0, fa0, fb0) > 0.f));
                u64 bal1 = __ballot((ocB < COUT) && (fmaf(v1, fa1, fb1) > 0.f));
                u64 w_lo = (bal0 & 0xffffffffull) | (bal1 << 32);
                u64 w_hi = (bal0 >> 32) | (bal1 & 0xffffffff00000000ull);
                int img  = wm >> 1;
                int pyo  = (wm & 1) * 4 + ag;
                int pxo0 = ((g >> 1) & 1) | (((g >> 2) & 1) << 2);
                size_t rowb = ((size_t)(b0i + img) * (TH / 2) + pyo) * (TW / 2);
                if (lane == (ag * 4 + gi) * 2)
                    outp[(rowb + pxo0) * OCW + gw] = w_lo;
                else if (lane == (ag * 4 + gi) * 2 + 1)
                    outp[(rowb + pxo0 + 2) * OCW + gw] = w_hi;
            }
        } else {
#pragma unroll
            for (int reg = 0; reg < 16; ++reg) {
                u64 bal0 = __ballot((ocA < COUT) && (fmaf(acc[ag][0][reg], fa0, fb0) > 0.f));
                u64 bal1 = __ballot((ocB < COUT) && (fmaf(acc[ag][1][reg], fa1, fb1) > 0.f));
                u64 w_lo = (bal0 & 0xffffffffull) | (bal1 << 32);
                u64 w_hi = (bal0 >> 32) | (bal1 & 0xffffffff00000000ull);
                int row  = (reg & 3) + 8 * (reg >> 2);
                int p_lo = wm * 128 + ag * 32 + row;
                int p_hi = p_lo + 4;
                if (lane == reg * 2) {
                    int img, py, px;
                    if constexpr (TW == 32) { img = 0; py = p_lo >> 5; px = p_lo & 31; }
                    else { img = p_lo >> 8; py = (p_lo >> 4) & 15; px = p_lo & 15; }
                    outp[(((size_t)(b0i + img) * H + (y0 + py)) * W + px) * OCW + gw] = w_lo;
                } else if (lane == reg * 2 + 1) {
                    int img, py, px;
                    if constexpr (TW == 32) { img = 0; py = p_hi >> 5; px = p_hi & 31; }
                    else { img = p_hi >> 8; py = (p_hi >> 4) & 15; px = p_hi & 15; }
                    outp[(((size_t)(b0i + img) * H + (y0 + py)) * W + px) * OCW + gw] = w_hi;
                }
            }
        }
    }
}

// ---------------------------------------------------------------------------
// fp4 8x8-layer conv: block = 4 waves = 4 images x 64 oc; wave = own image,
// B from global with 1-step register prefetch; 9 taps/chunk, K=64.
// ---------------------------------------------------------------------------
template <int KWIN, int OCG, int OCW, int COUT, bool POOL>
__global__ __launch_bounds__(256, 3)
void conv_m8f(const u64* __restrict__ act, const char* __restrict__ wb,
              const float* __restrict__ sA, const float* __restrict__ sB,
              u64* __restrict__ outp)
{
    constexpr int CELLS = 100;
    constexpr int PLANE = CELLS * 16;
    constexpr int IMG = 2 * PLANE;
    __shared__ __attribute__((aligned(16))) char smem[4 * IMG];

    const int tid  = threadIdx.x;
    const int lane = tid & 63;
    const int wave = tid >> 6;
    const int h    = lane >> 5;
    const int m    = lane & 31;

    const int b = blockIdx.x * 4 + wave;
    const int ocg0 = blockIdx.y * 2;
    const int gw = blockIdx.y;

    int aoff[2];
#pragma unroll
    for (int ph = 0; ph < 2; ++ph) {
        int p = ph * 32 + m;
        aoff[ph] = wave * IMG + ((p >> 3) * 10 + (p & 7)) * 16 + h * PLANE;
    }

    v16f acc[2][2];
#pragma unroll
    for (int a = 0; a < 2; ++a)
#pragma unroll
        for (int o = 0; o < 2; ++o)
#pragma unroll
            for (int i = 0; i < 16; ++i) acc[a][o][i] = 0.0f;

    const u64* actb = act + (size_t)b * (64 * KWIN);

    v4i b0n, b1n;
    {
        const v4i* pn = (const v4i*)(wb + ((size_t)ocg0) * 1024) + lane;
        b0n = pn[0]; b1n = pn[64];
    }

#pragma unroll 1
    for (int c64 = 0; c64 < KWIN; ++c64) {
        for (int cell = lane; cell < CELLS; cell += 64) {
            int cy = cell / 10, cx = cell % 10;
            int gy = cy - 1, gx = cx - 1;
            char* dst = smem + wave * IMG + cell * 16;
            if ((unsigned)gy < 8u && (unsigned)gx < 8u) {
                u64 wd = actb[((size_t)gy * 8 + gx) * KWIN + c64];
                *(v4i*)dst           = fp4_unpack32((unsigned)wd);
                *(v4i*)(dst + PLANE) = fp4_unpack32((unsigned)(wd >> 32));
            } else {
                v4i z = {0, 0, 0, 0};
                *(v4i*)dst           = z;
                *(v4i*)(dst + PLANE) = z;
            }
        }
        __syncthreads();

#pragma unroll
        for (int t = 0; t < 9; ++t) {
            v4i b0 = b0n, b1 = b1n;
            {
                const int tn = (t + 1) % 9;
                const int cn = (t == 8) ? (c64 + 1) : c64;
                const v4i* pn = (const v4i*)(wb + ((size_t)((tn * KWIN + cn) * OCG + ocg0)) * 1024) + lane;
                b0n = pn[0]; b1n = pn[64];
            }
            const int toff = ((t / 3) * 10 + (t % 3)) * 16;
            v4i a0 = *(const v4i*)(smem + aoff[0] + toff);
            v4i a1 = *(const v4i*)(smem + aoff[1] + toff);
            acc[0][0] = mfma_fp4(a0, b0, acc[0][0]);
            acc[1][0] = mfma_fp4(a1, b0, acc[1][0]);
            acc[0][1] = mfma_fp4(a0, b1, acc[0][1]);
            acc[1][1] = mfma_fp4(a1, b1, acc[1][1]);
        }
        __syncthreads();
    }

    const int ocA = ocg0 * 32 + m;
    const int ocB = ocA + 32;
    const float fa0 = sA[ocA < COUT ? ocA : 0], fb0 = sB[ocA < COUT ? ocA : 0];
    const float fa1 = sA[ocB < COUT ? ocB : 0], fb1 = sB[ocB < COUT ? ocB : 0];

#pragma unroll
    for (int ph = 0; ph < 2; ++ph) {
        if constexpr (POOL) {
#pragma unroll
            for (int gi = 0; gi < 4; ++gi) {
                const int g = (gi & 1) * 2 + (gi >> 1) * 8;
                float v0 = fmaxf(fmaxf(acc[ph][0][g], acc[ph][0][g ^ 1]),
                                 fmaxf(acc[ph][0][g ^ 4], acc[ph][0][(g ^ 4) | 1]));
                float v1 = fmaxf(fmaxf(acc[ph][1][g], acc[ph][1][g ^ 1]),
                                 fmaxf(acc[ph][1][g ^ 4], acc[ph][1][(g ^ 4) | 1]));
                u64 bal0 = __ballot((ocA < COUT) && (fmaf(v0, fa0, fb0) > 0.f));
                u64 bal1 = __ballot((ocB < COUT) && (fmaf(v1, fa1, fb1) > 0.f));
                u64 w_lo = (bal0 & 0xffffffffull) | (bal1 << 32);
                u64 w_hi = (bal0 >> 32) | (bal1 & 0xffffffff00000000ull);
                int pyo  = ph * 2 + ((g >> 3) & 1);
                int pxo0 = (g >> 1) & 1;
                int pxo1 = pxo0 | 2;
                size_t rowb = ((size_t)b * 4 + pyo) * 4;
                if (lane == (ph * 4 + gi) * 2)
                    outp[(rowb + pxo0) * OCW + gw] = w_lo;
                else if (lane == (ph * 4 + gi) * 2 + 1)
                    outp[(rowb + pxo1) * OCW + gw] = w_hi;
            }
        } else {
#pragma unroll
            for (int reg = 0; reg < 16; ++reg) {
                u64 bal0 = __ballot((ocA < COUT) && (fmaf(acc[ph][0][reg], fa0, fb0) > 0.f));
                u64 bal1 = __ballot((ocB < COUT) && (fmaf(acc[ph][1][reg], fa1, fb1) > 0.f));
                u64 w_lo = (bal0 & 0xffffffffull) | (bal1 << 32);
                u64 w_hi = (bal0 >> 32) | (bal1 & 0xffffffff00000000ull);
                int row  = (reg & 3) + 8 * (reg >> 2);
                int p_lo = ph * 32 + row;
                int p_hi = p_lo + 4;
                if (lane == reg * 2)
                    outp[(((size_t)b * 8 + (p_lo >> 3)) * 8 + (p_lo & 7)) * OCW + gw] = w_lo;
                else if (lane == reg * 2 + 1)
                    outp[(((size_t)b * 8 + (p_hi >> 3)) * 8 + (p_hi & 7)) * OCW + gw] = w_hi;
            }
        }
    }
}

// ---------------------------------------------------------------------------
// FC: out[b][k] = 15568 - 2*popcount(a6[b] ^ wfc[k]) + fcb[k]   (exact)
// ---------------------------------------------------------------------------
__global__ void fc_kernel(const u64* __restrict__ a6, const u64* __restrict__ wfc,
                          const float* __restrict__ fcb, float* __restrict__ out)
{
    int idx = blockIdx.x * blockDim.x + threadIdx.x;
    if (idx >= 2560) return;
    int k = idx % 10, b = idx / 10;
    const u64* ap = a6 + (size_t)b * 256;
    const u64* wq = wfc + (size_t)k * 256;
    int pop = 0;
#pragma unroll 8
    for (int q = 0; q < 256; ++q) pop += __popcll(ap[q] ^ wq[q]);
    out[idx] = (float)(15568 - 2 * pop) + fcb[k];
}

// ---------------------------------------------------------------------------
// launch
// ---------------------------------------------------------------------------
extern "C" void kernel_launch(void* const* d_in, const int* in_sizes, int n_in,
                              void* d_out, int out_size, void* d_ws, size_t ws_size,
                              hipStream_t stream)
{
    const float* x   = (const float*)d_in[0];
    const float* w0  = (const float*)d_in[1];
    const float* p0  = (const float*)d_in[2];
    const float* w1  = (const float*)d_in[3];
    const float* p1  = (const float*)d_in[4];
    const float* w2  = (const float*)d_in[5];
    const float* p2  = (const float*)d_in[6];
    const float* w3  = (const float*)d_in[7];
    const float* p3  = (const float*)d_in[8];
    const float* w4  = (const float*)d_in[9];
    const float* p4  = (const float*)d_in[10];
    const float* w5  = (const float*)d_in[11];
    const float* p5  = (const float*)d_in[12];
    const float* fcw = (const float*)d_in[13];
    const float* fcb = (const float*)d_in[14];
    float* out = (float*)d_out;

    u64* WS = (u64*)d_ws;
    u64* A0 = WS;                  // [256][32][32][1]  = 262144
    u64* A1 = A0 + 262144;         // [256][32][32][6]  = 1572864
    u64* A2 = A1 + 1572864;        // [256][16][16][6]  = 393216
    u64* A3 = A2 + 393216;         // [256][16][16][11] = 720896
    u64* A4 = A3 + 720896;         // [256][8][8][11]   = 180224
    u64* A5 = A4 + 180224;         // [256][8][8][20]   = 327680
    u64* A6 = A5 + 327680;         // [256][4][4][16]   = 65536
    u64* WFp = A6 + 65536;         // 2560
    // fp4 weight slabs: 9*KWIN*OCG KB each
    char* WB0 = (char*)(WFp + 2560);   //   110,592 (KWIN=1,  OCG=12)
    char* WB1 = WB0 + 110592;          //   663,552 (KWIN=6,  OCG=12)
    char* WB2 = WB1 + 663552;          // 1,327,104 (KWIN=6,  OCG=24)
    char* WB3 = WB2 + 1327104;         // 2,433,024 (KWIN=11, OCG=24)
    char* WB4 = WB3 + 2433024;         // 4,055,040 (KWIN=11, OCG=40)
    char* WB5 = WB4 + 4055040;         // 5,898,240 (KWIN=20, OCG=32)
    float* SA0 = (float*)(WB5 + 5898240);
    float* SB0 = SA0 + 1280;
    float* SA1 = SB0 + 1280;
    float* SB1 = SA1 + 1280;
    float* SA2 = SB1 + 1280;
    float* SB2 = SA2 + 1280;
    float* SA3 = SB2 + 1280;
    float* SB3 = SA3 + 1280;
    float* SA4 = SB3 + 1280;
    float* SB4 = SA4 + 1280;
    float* SA5 = SB4 + 1280;
    float* SB5 = SA5 + 1280;
    // total ws ~= 43 MB

    pack_input_kernel<<<1024, 256, 0, stream>>>(x, A0);
    pack_w_fp4<<<(9 * 1 * 12 * 64 + 255) / 256, 256, 0, stream>>>(w0, (unsigned*)WB0, 344, 3, 1, 12);
    pack_w_fp4<<<(9 * 6 * 12 * 64 + 255) / 256, 256, 0, stream>>>(w1, (unsigned*)WB1, 352, 344, 6, 12);
    pack_w_fp4<<<(9 * 6 * 24 * 64 + 255) / 256, 256, 0, stream>>>(w2, (unsigned*)WB2, 686, 352, 6, 24);
    pack_w_fp4<<<(9 * 11 * 24 * 64 + 255) / 256, 256, 0, stream>>>(w3, (unsigned*)WB3, 679, 686, 11, 24);
    pack_w_fp4<<<(9 * 11 * 40 * 64 + 255) / 256, 256, 0, stream>>>(w4, (unsigned*)WB4, 1246, 679, 11, 40);
    pack_w_fp4<<<(9 * 20 * 32 * 64 + 255) / 256, 256, 0, stream>>>(w5, (unsigned*)WB5, 973, 1246, 20, 32);
    pack_bn_kernel<<<2, 256, 0, stream>>>(p0, SA0, SB0, 344);
    pack_bn_kernel<<<2, 256, 0, stream>>>(p1, SA1, SB1, 352);
    pack_bn_kernel<<<3, 256, 0, stream>>>(p2, SA2, SB2, 686);
    pack_bn_kernel<<<3, 256, 0, stream>>>(p3, SA3, SB3, 679);
    pack_bn_kernel<<<5, 256, 0, stream>>>(p4, SA4, SB4, 1246);
    pack_bn_kernel<<<4, 256, 0, stream>>>(p5, SA5, SB5, 973);
    pack_fc_kernel<<<10, 256, 0, stream>>>(fcw, WFp);

    // conv layers: conv_v6f<H,W,TH,TW,NIMG,KWIN,OCG_T,OCW,COUT,POOL>
    conv_v6f<32, 32, 16, 32, 1,  1, 12,  6, 344, false>
        <<<dim3(512, 6), 256, 0, stream>>>(A0, WB0, SA0, SB0, A1);
    conv_v6f<32, 32, 16, 32, 1,  6, 12,  6, 352, true>
        <<<dim3(512, 6), 256, 0, stream>>>(A1, WB1, SA1, SB1, A2);
    conv_v6f<16, 16, 16, 16, 2,  6, 24, 11, 686, false>
        <<<dim3(128, 11), 256, 0, stream>>>(A2, WB2, SA2, SB2, A3);
    conv_v6f<16, 16, 16, 16, 2, 11, 24, 11, 679, true>
        <<<dim3(128, 11), 256, 0, stream>>>(A3, WB3, SA3, SB3, A4);
    conv_m8f<11, 40, 20, 1246, false>
        <<<dim3(64, 20), 256, 0, stream>>>(A4, WB4, SA4, SB4, A5);
    conv_m8f<20, 32, 16, 973, true>
        <<<dim3(64, 16), 256, 0, stream>>>(A5, WB5, SA5, SB5, A6);

    fc_kernel<<<10, 256, 0, stream>>>(A6, WFp, fcb, out);
}